// Round 10
// baseline (381.920 us; speedup 1.0000x reference)
//
#include <hip/hip_runtime.h>
#include <cmath>

// ---------------- problem constants ----------------
constexpr int BSZ = 16, T = 32, NOBJ = 100;
constexpr int GLOVE = 300, GEMB = 64, ADIM = 10, GCN_DIM = 512, Hh = 512, ASPACE = 6, RES = 512;
constexpr int Bt = BSZ * T;          // 512
constexpr int FUSED_IN = RES + GEMB + ADIM + GCN_DIM; // 1098
constexpr int FP = 1120;             // padded fused width

typedef __attribute__((ext_vector_type(8))) short bf16x8;
typedef __attribute__((ext_vector_type(4))) float f32x4;

__device__ __forceinline__ unsigned short f2bf(float f) {
    unsigned u = __float_as_uint(f);
    return (unsigned short)((u + 0x7FFFu + ((u >> 16) & 1u)) >> 16);
}
__device__ __forceinline__ unsigned pk2(float a, float b) {
    return (unsigned)f2bf(a) | ((unsigned)f2bf(b) << 16);
}
__device__ __forceinline__ float sigf(float x) { return 1.f / (1.f + __expf(-x)); }

// ---------------- mgemm: C = A @ B^T (+bias)(relu), bf16 in, fp32 acc ----------------
// 4-deep software pipeline, static stage indices (no scratch). Requires K>=128 here (all
// call sites satisfy), M%64==0, N%64==0, K%32==0, lda/ldb%8==0.
template<bool RELU, int OMODE>  // OMODE: 0=fp32 out, 1=bf16 out
__global__ __launch_bounds__(256)
void mgemm(const unsigned short* __restrict__ A, int lda,
           const unsigned short* __restrict__ B, int ldb,
           float* __restrict__ Cf, unsigned short* __restrict__ Cb, int ldc,
           const float* __restrict__ bias, int K)
{
    const int tid = threadIdx.x;
    const int l = tid & 63, wv = tid >> 6;
    const int m0 = blockIdx.y * 64 + wv * 16;
    const int n0 = blockIdx.x * 64;
    const int lr = l & 15, kg = l >> 4;
    const unsigned short* ap = A + (long)(m0 + lr) * lda + kg * 8;
    const unsigned short* bp = B + (long)(n0 + lr) * ldb + kg * 8;
    const int nk = K >> 5;
    f32x4 acc0 = (f32x4){0.f, 0.f, 0.f, 0.f};
    f32x4 acc1 = acc0, acc2 = acc0, acc3 = acc0;
    bf16x8 a_[4], b0_[4], b1_[4], b2_[4], b3_[4];
#pragma unroll
    for (int s = 0; s < 4; ++s) {
        if (s < nk) {
            int k = s * 32;
            a_[s]  = *(const bf16x8*)(ap + k);
            b0_[s] = *(const bf16x8*)(bp + k);
            b1_[s] = *(const bf16x8*)(bp + 16 * ldb + k);
            b2_[s] = *(const bf16x8*)(bp + 32 * ldb + k);
            b3_[s] = *(const bf16x8*)(bp + 48 * ldb + k);
        }
    }
    for (int i = 0; i < nk; i += 4) {
#pragma unroll
        for (int s = 0; s < 4; ++s) {
            if (i + s < nk) {
                acc0 = __builtin_amdgcn_mfma_f32_16x16x32_bf16(a_[s], b0_[s], acc0, 0, 0, 0);
                acc1 = __builtin_amdgcn_mfma_f32_16x16x32_bf16(a_[s], b1_[s], acc1, 0, 0, 0);
                acc2 = __builtin_amdgcn_mfma_f32_16x16x32_bf16(a_[s], b2_[s], acc2, 0, 0, 0);
                acc3 = __builtin_amdgcn_mfma_f32_16x16x32_bf16(a_[s], b3_[s], acc3, 0, 0, 0);
                if (i + s + 4 < nk) {
                    int k = (i + s + 4) * 32;
                    a_[s]  = *(const bf16x8*)(ap + k);
                    b0_[s] = *(const bf16x8*)(bp + k);
                    b1_[s] = *(const bf16x8*)(bp + 16 * ldb + k);
                    b2_[s] = *(const bf16x8*)(bp + 32 * ldb + k);
                    b3_[s] = *(const bf16x8*)(bp + 48 * ldb + k);
                }
            }
        }
    }
    f32x4 av[4] = {acc0, acc1, acc2, acc3};
#pragma unroll
    for (int nf = 0; nf < 4; ++nf) {
        int n = n0 + nf * 16 + lr;
        float bs = bias ? bias[n] : 0.f;
#pragma unroll
        for (int r = 0; r < 4; ++r) {
            float val = av[nf][r] + bs;
            if (RELU) val = fmaxf(val, 0.f);
            long idx = (long)(m0 + kg * 4 + r) * ldc + n;
            if (OMODE == 0) Cf[idx] = val;
            else            Cb[idx] = f2bf(val);
        }
    }
}

// ---------------- fp32 GEMM for tiny ragged cases (word, v) ----------------
template<bool RELU>
__global__ __launch_bounds__(128)
void gemm32(const float* __restrict__ A, int lda,
            const float* __restrict__ B, int ldb,
            float* __restrict__ C, int ldc,
            const float* __restrict__ bias, int M, int N, int K)
{
    __shared__ float As[32][36];
    __shared__ float Bs[32][68];
    const int tid = threadIdx.x;
    const int m0 = blockIdx.y * 32, n0 = blockIdx.x * 64;
    const int mi = tid >> 4, ni = tid & 15;
    float acc[4][4] = {};
    for (int k0 = 0; k0 < K; k0 += 32) {
        __syncthreads();
#pragma unroll
        for (int l = 0; l < 2; ++l) {
            int e = tid + l * 128;
            int row = e >> 3, kq = (e & 7) << 2;
            float4 va = make_float4(0.f, 0.f, 0.f, 0.f);
            if (m0 + row < M && k0 + kq < K)
                va = *(const float4*)&A[(long)(m0 + row) * lda + k0 + kq];
            As[kq + 0][row] = va.x; As[kq + 1][row] = va.y;
            As[kq + 2][row] = va.z; As[kq + 3][row] = va.w;
        }
#pragma unroll
        for (int l = 0; l < 4; ++l) {
            int e = tid + l * 128;
            int row = e >> 3, kq = (e & 7) << 2;
            float4 vb = make_float4(0.f, 0.f, 0.f, 0.f);
            if (n0 + row < N && k0 + kq < K)
                vb = *(const float4*)&B[(long)(n0 + row) * ldb + k0 + kq];
            Bs[kq + 0][row] = vb.x; Bs[kq + 1][row] = vb.y;
            Bs[kq + 2][row] = vb.z; Bs[kq + 3][row] = vb.w;
        }
        __syncthreads();
#pragma unroll
        for (int k = 0; k < 32; ++k) {
            float4 a4 = *(const float4*)&As[k][4 * mi];
            float4 b4 = *(const float4*)&Bs[k][4 * ni];
            acc[0][0] = fmaf(a4.x, b4.x, acc[0][0]); acc[0][1] = fmaf(a4.x, b4.y, acc[0][1]);
            acc[0][2] = fmaf(a4.x, b4.z, acc[0][2]); acc[0][3] = fmaf(a4.x, b4.w, acc[0][3]);
            acc[1][0] = fmaf(a4.y, b4.x, acc[1][0]); acc[1][1] = fmaf(a4.y, b4.y, acc[1][1]);
            acc[1][2] = fmaf(a4.y, b4.z, acc[1][2]); acc[1][3] = fmaf(a4.y, b4.w, acc[1][3]);
            acc[2][0] = fmaf(a4.z, b4.x, acc[2][0]); acc[2][1] = fmaf(a4.z, b4.y, acc[2][1]);
            acc[2][2] = fmaf(a4.z, b4.z, acc[2][2]); acc[2][3] = fmaf(a4.z, b4.w, acc[2][3]);
            acc[3][0] = fmaf(a4.w, b4.x, acc[3][0]); acc[3][1] = fmaf(a4.w, b4.y, acc[3][1]);
            acc[3][2] = fmaf(a4.w, b4.z, acc[3][2]); acc[3][3] = fmaf(a4.w, b4.w, acc[3][3]);
        }
    }
    const int n = n0 + 4 * ni;
    if (n >= N) return;
    float4 bv = make_float4(0.f, 0.f, 0.f, 0.f);
    if (bias) bv = *(const float4*)&bias[n];
#pragma unroll
    for (int r = 0; r < 4; ++r) {
        int m = m0 + 4 * mi + r;
        if (m >= M) continue;
        float4 v;
        v.x = acc[r][0] + bv.x; v.y = acc[r][1] + bv.y;
        v.z = acc[r][2] + bv.z; v.w = acc[r][3] + bv.w;
        if (RELU) {
            v.x = fmaxf(v.x, 0.f); v.y = fmaxf(v.y, 0.f);
            v.z = fmaxf(v.z, 0.f); v.w = fmaxf(v.w, 0.f);
        }
        *(float4*)&C[(long)m * ldc + n] = v;
    }
}

// ---------------- x1pack: generate X1 in MFMA fragment order (bf16) ----------------
// X1g[b*3584 + mt*512 + kt*64 + l] (uint4) = 8 bf16 of X1[b][mt*16+(l&15)][kt*32+(l>>4)*8 ..]
__global__ __launch_bounds__(256)
void x1pack(const float* __restrict__ u, const float* __restrict__ v,
            const float* __restrict__ rowsum, uint4* __restrict__ X1g)
{
    __shared__ float u_lds[256];
    __shared__ float rs_lds[112];
    const int b = blockIdx.x, tid = threadIdx.x;
    u_lds[tid] = u[(long)b * 256 + tid];
    if (tid < 112) rs_lds[tid] = (tid < 100) ? rowsum[tid] : 0.f;
    __syncthreads();
    uint4* outp = X1g + (size_t)b * 3584;
#pragma unroll
    for (int it = 0; it < 14; ++it) {
        int job = it * 256 + tid;
        int l = job & 63;
        int kt = (job >> 6) & 7;
        int mt = job >> 9;
        int n = mt * 16 + (l & 15);
        int k0 = kt * 32 + ((l >> 4) << 3);
        uint4 p = make_uint4(0, 0, 0, 0);
        if (n < 100) {
            float rsn = rs_lds[n];
            float4 u0 = *(const float4*)&u_lds[k0];
            float4 u1 = *(const float4*)&u_lds[k0 + 4];
            const float4* vp = (const float4*)&v[n * 256 + k0];
            float4 v0 = vp[0], v1 = vp[1];
            float x0 = fmaxf(fmaf(rsn, u0.x, v0.x), 0.f), x1 = fmaxf(fmaf(rsn, u0.y, v0.y), 0.f);
            float x2 = fmaxf(fmaf(rsn, u0.z, v0.z), 0.f), x3 = fmaxf(fmaf(rsn, u0.w, v0.w), 0.f);
            float x4 = fmaxf(fmaf(rsn, u1.x, v1.x), 0.f), x5 = fmaxf(fmaf(rsn, u1.y, v1.y), 0.f);
            float x6 = fmaxf(fmaf(rsn, u1.z, v1.z), 0.f), x7 = fmaxf(fmaf(rsn, u1.w, v1.w), 0.f);
            p = make_uint4(pk2(x0, x1), pk2(x2, x3), pk2(x4, x5), pk2(x6, x7));
        }
        outp[job] = p;
    }
}

// ---------------- gcn_core: Z1=X1@W1^T (frag stream, no barriers) -> X2=A@Z1 -> s -> x3 ----------------
constexpr int ZLD = 152;   // Z1T stride in shorts

__global__ __launch_bounds__(256, 2)
void gcn_core(const bf16x8* __restrict__ X1g,   // [b][7mt][8kt][64l] frags
              const float* __restrict__ Aglob,  // [100,100] fp32
              const bf16x8* __restrict__ W1f,   // [16jt][8kt][64l] frags
              const bf16x8* __restrict__ Af,    // [7mt][4kt][64l] frags
              const float* __restrict__ w2,     // [256]
              unsigned short* __restrict__ x3b) // [512,128] bf16
{
    __shared__ unsigned short Z1Ts[128 * ZLD];
    __shared__ float w2l[256];
    __shared__ float spart[4][112];
    __shared__ float sl[112];

    const int b = blockIdx.x, tid = threadIdx.x;
    const int l = tid & 63, wv = tid >> 6;
    const int lrow = l & 15, kg = l >> 4;

    w2l[tid] = w2[tid];
    if (tid < 128) {
        uint4 z = make_uint4(0, 0, 0, 0);
        *(uint4*)&Z1Ts[tid * ZLD + 112] = z;
        *(uint4*)&Z1Ts[tid * ZLD + 120] = z;
    }
    if (tid < 28) x3b[(long)b * 128 + 100 + tid] = 0;
    __syncthreads();

    const bf16x8* xb = X1g + (size_t)b * 3584 + l;

    float sacc[7][4];
#pragma unroll
    for (int mt = 0; mt < 7; ++mt)
#pragma unroll
        for (int r = 0; r < 4; ++r) sacc[mt][r] = 0.f;

    for (int half = 0; half < 2; ++half) {
        f32x4 acc1[7][2];
#pragma unroll
        for (int mt = 0; mt < 7; ++mt)
#pragma unroll
            for (int jtl = 0; jtl < 2; ++jtl) acc1[mt][jtl] = (f32x4){0.f, 0.f, 0.f, 0.f};

#pragma unroll
        for (int kt = 0; kt < 8; ++kt) {
            bf16x8 af[7];
#pragma unroll
            for (int mt = 0; mt < 7; ++mt)
                af[mt] = xb[mt * 512 + kt * 64];
#pragma unroll
            for (int jtl = 0; jtl < 2; ++jtl) {
                int jt = half * 8 + wv * 2 + jtl;
                bf16x8 bfr = W1f[(jt * 8 + kt) * 64 + l];
#pragma unroll
                for (int mt = 0; mt < 7; ++mt)
                    acc1[mt][jtl] = __builtin_amdgcn_mfma_f32_16x16x32_bf16(af[mt], bfr, acc1[mt][jtl], 0, 0, 0);
            }
        }

        // write Z1T (wave-private rows), bf16
#pragma unroll
        for (int mt = 0; mt < 7; ++mt)
#pragma unroll
            for (int jtl = 0; jtl < 2; ++jtl) {
                int jloc = (wv * 2 + jtl) * 16 + lrow;
                f32x4 a = acc1[mt][jtl];
                uint2 zz;
                zz.x = pk2(a[0], a[1]);
                zz.y = pk2(a[2], a[3]);
                *(uint2*)&Z1Ts[jloc * ZLD + mt * 16 + kg * 4] = zz;
            }

        // phase 2: X2 = A @ Z1 (same-wave read of just-written rows)
        bf16x8 bz[2][4];
#pragma unroll
        for (int jtl = 0; jtl < 2; ++jtl)
#pragma unroll
            for (int k2 = 0; k2 < 4; ++k2)
                bz[jtl][k2] = *(const bf16x8*)&Z1Ts[((wv * 2 + jtl) * 16 + lrow) * ZLD + k2 * 32 + kg * 8];
#pragma unroll
        for (int mt = 0; mt < 7; ++mt) {
            bf16x8 aA[4];
#pragma unroll
            for (int k2 = 0; k2 < 4; ++k2) aA[k2] = Af[(mt * 4 + k2) * 64 + l];
#pragma unroll
            for (int jtl = 0; jtl < 2; ++jtl) {
                f32x4 p = (f32x4){0.f, 0.f, 0.f, 0.f};
#pragma unroll
                for (int k2 = 0; k2 < 4; ++k2)
                    p = __builtin_amdgcn_mfma_f32_16x16x32_bf16(aA[k2], bz[jtl][k2], p, 0, 0, 0);
                float w2j = w2l[half * 128 + (wv * 2 + jtl) * 16 + lrow];
#pragma unroll
                for (int r = 0; r < 4; ++r)
                    sacc[mt][r] = fmaf(fmaxf(p[r], 0.f), w2j, sacc[mt][r]);
            }
        }
    }

    // reduce sacc over j (low 4 lane bits) -> spart
#pragma unroll
    for (int mt = 0; mt < 7; ++mt) {
        float s0 = sacc[mt][0], s1 = sacc[mt][1], s2 = sacc[mt][2], s3 = sacc[mt][3];
#pragma unroll
        for (int off = 1; off < 16; off <<= 1) {
            s0 += __shfl_xor(s0, off);
            s1 += __shfl_xor(s1, off);
            s2 += __shfl_xor(s2, off);
            s3 += __shfl_xor(s3, off);
        }
        if (lrow == 0) {
            int m = mt * 16 + kg * 4;
            spart[wv][m + 0] = s0; spart[wv][m + 1] = s1;
            spart[wv][m + 2] = s2; spart[wv][m + 3] = s3;
        }
    }
    __syncthreads();
    if (tid < 112)
        sl[tid] = spart[0][tid] + spart[1][tid] + spart[2][tid] + spart[3][tid];
    __syncthreads();

    // phase 3: x3[b,n] = relu(sum_m A[n,m]*s[m])
    float sv0 = (l < 100) ? sl[l] : 0.f;
    float sv1 = (l + 64 < 100) ? sl[l + 64] : 0.f;
#pragma unroll 5
    for (int i = 0; i < 25; ++i) {
        int n = i * 4 + wv;
        float a0 = (l < 100) ? Aglob[n * 100 + l] : 0.f;
        float a1 = (l + 64 < 100) ? Aglob[n * 100 + l + 64] : 0.f;
        float p = a0 * sv0 + a1 * sv1;
#pragma unroll
        for (int off = 32; off; off >>= 1) p += __shfl_xor(p, off);
        if (l == 0) x3b[(long)b * 128 + n] = f2bf(fmaxf(p, 0.f));
    }
}

// ---------------- persistent LSTM: one launch, 32 steps, grid spin-barrier ----------------
// 32 blocks x 256 thr. Block bid owns jh slice [bid*16,+16); wave g = gate type.
// Whh fragments preloaded to registers (16 x bf16x8). c kept in one register per thread.
__global__ __launch_bounds__(256)
void lstm_persist(const float* __restrict__ xWih,           // [512][2048], rows b*T+t
                  const bf16x8* __restrict__ Whhf,
                  unsigned short* __restrict__ hbA,         // ping (zeroed)
                  unsigned short* __restrict__ hbB,         // pong
                  float* __restrict__ cBuf,                 // [16][512] final c
                  float* __restrict__ hFin,                 // [16][512] final h
                  unsigned short* __restrict__ sfb,
                  unsigned* __restrict__ bar)               // zeroed counter
{
    __shared__ float gl[4][16][17];
    const int tid = threadIdx.x;
    const int l = tid & 63, g = tid >> 6;
    const int bid = blockIdx.x;
    const int jt = g * 32 + bid;
    const int lr = l & 15, kg = l >> 4;
    const bf16x8* wp = Whhf + (size_t)jt * 16 * 64 + l;
    bf16x8 w[16];
#pragma unroll
    for (int kt = 0; kt < 16; ++kt) w[kt] = wp[kt * 64];
    const int fb = tid >> 4, jl = tid & 15;
    const int jh = bid * 16 + jl;
    float c_reg = 0.f;
    const unsigned short* hprev = hbA;
    unsigned short* hnext = hbB;
    for (int t = 0; t < T; ++t) {
        const unsigned short* hp = hprev + lr * 512 + kg * 8;
        f32x4 acc = (f32x4){0.f, 0.f, 0.f, 0.f};
#pragma unroll
        for (int kt = 0; kt < 16; ++kt) {
            bf16x8 a = *(const bf16x8*)(hp + kt * 32);
            acc = __builtin_amdgcn_mfma_f32_16x16x32_bf16(a, w[kt], acc, 0, 0, 0);
        }
#pragma unroll
        for (int r = 0; r < 4; ++r) gl[g][kg * 4 + r][lr] = acc[r];
        __syncthreads();
        const float* xw = xWih + (size_t)(fb * T + t) * 2048;
        float gi = gl[0][fb][jl] + xw[jh];
        float gf = gl[1][fb][jl] + xw[512 + jh];
        float gg = gl[2][fb][jl] + xw[1024 + jh];
        float go = gl[3][fb][jl] + xw[1536 + jh];
        float cn = sigf(gf) * c_reg + sigf(gi) * tanhf(gg);
        float hn = sigf(go) * tanhf(cn);
        c_reg = cn;
        hnext[fb * 512 + jh] = f2bf(hn);
        sfb[(size_t)(fb * T + t) * 512 + jh] = f2bf(hn);
        if (t == T - 1) { hFin[fb * 512 + jh] = hn; cBuf[fb * 512 + jh] = cn; }
        // grid barrier: release h writes, count, acquire
        __syncthreads();                       // drains this block's stores (vmcnt before s_barrier)
        if (tid == 0) {
            __threadfence();                   // device-scope release
            atomicAdd(bar, 1u);
            unsigned target = 32u * (unsigned)(t + 1);
            while (atomicAdd(bar, 0u) < target) { }   // RMW poll at coherence point
            __threadfence();                   // device-scope acquire
        }
        __syncthreads();
        const unsigned short* tmp = hprev; hprev = hnext; hnext = (unsigned short*)tmp;
    }
}

// ---------------- glue kernels ----------------
__global__ void k_aw_rowsum(const float* __restrict__ A, const float* __restrict__ word,
                            float* __restrict__ Aw, float* __restrict__ rowsum)
{
    int i = blockIdx.x * 256 + threadIdx.x;
    if (i < 6400) {
        int n = i / 64, k = i % 64;
        float s = 0.f;
        for (int m = 0; m < 100; ++m) s += A[n * 100 + m] * word[m * 64 + k];
        Aw[i] = s;
    } else if (i < 6500) {
        int n = i - 6400;
        float s = 0.f;
        for (int m = 0; m < 100; ++m) s += A[n * 100 + m];
        rowsum[n] = s;
    }
}

// preprocessing segments (blocks of 256):
//  [0,512)        Whhf bf16 frag-major
//  [512,2752)     WfPb [512][1120] pad bf16
//  [2752,6848)    Wihb [2048][512] bf16
//  [6848,7360)    Whdb [256][512] = Wa1|Wc1 bf16
//  [7360,7361)    bhd = ba1|bc1
//  [7361,7441)    Wgb [64][320] pad bf16
//  [7441,7953)    W0ab [256][512] bf16
//  [7953,8209)    Wfmb [512][128] pad bf16
//  [8209,8849)    tgtb [512][320] pad bf16
//  [8849,9873)    featsb [512][512] bf16
//  [9873,10897)   fusedb cols 0..512 = feats bf16
//  [10897,10917)  fusedb cols 576..586 = act_e
//  [10917,10961)  fusedb cols 1098..1120 = 0
//  [10961,10993)  hbA zero (8192 bf16)
//  [10993,10994)  bar zero
//  [10994,11002)  bsum
//  [11002,11034)  W1frag
//  [11034,11041)  Afrag
__global__ void k_prep(const float* __restrict__ Whh, uint4* __restrict__ Whhf,
                       const float* __restrict__ Wf, unsigned short* __restrict__ WfPb,
                       const float* __restrict__ Wih, unsigned short* __restrict__ Wihb,
                       const float* __restrict__ Wa1, const float* __restrict__ Wc1,
                       unsigned short* __restrict__ Whdb,
                       const float* __restrict__ ba1, const float* __restrict__ bc1,
                       float* __restrict__ bhd,
                       const float* __restrict__ Wg, unsigned short* __restrict__ Wgb,
                       const float* __restrict__ W0, unsigned short* __restrict__ W0ab,
                       const float* __restrict__ Wfm, unsigned short* __restrict__ Wfmb,
                       const float* __restrict__ target, unsigned short* __restrict__ tgtb,
                       const float* __restrict__ feats, unsigned short* __restrict__ featsb,
                       unsigned short* __restrict__ fusedb,
                       const float* __restrict__ aprob, const float* __restrict__ Wa,
                       const float* __restrict__ ba,
                       unsigned short* __restrict__ hbA, unsigned* __restrict__ bar,
                       const float* __restrict__ bih, const float* __restrict__ bhh,
                       float* __restrict__ bsum,
                       const float* __restrict__ W1, uint4* __restrict__ W1f,
                       const float* __restrict__ A, uint4* __restrict__ Af)
{
    int bx = blockIdx.x, tid = threadIdx.x;
    if (bx < 512) {
        int job = bx * 256 + tid;
        int jtkt = job >> 6, ll = job & 63;
        int j = (jtkt >> 4) * 16 + (ll & 15);
        int k0 = (jtkt & 15) * 32 + (ll >> 4) * 8;
        const float* src = &Whh[(long)j * 512 + k0];
        uint4 p;
        p.x = pk2(src[0], src[1]); p.y = pk2(src[2], src[3]);
        p.z = pk2(src[4], src[5]); p.w = pk2(src[6], src[7]);
        Whhf[job] = p;
    } else if (bx < 2752) {
        int i = (bx - 512) * 256 + tid;
        int r = i / FP, c = i - r * FP;
        WfPb[i] = f2bf(c < FUSED_IN ? Wf[(long)r * FUSED_IN + c] : 0.f);
    } else if (bx < 6848) {
        int i = (bx - 2752) * 256 + tid;
        Wihb[i] = f2bf(Wih[i]);
    } else if (bx < 7360) {
        int i = (bx - 6848) * 256 + tid;
        int r = i >> 9, c = i & 511;
        Whdb[i] = f2bf(r < 128 ? Wa1[r * 512 + c] : Wc1[(r - 128) * 512 + c]);
    } else if (bx < 7361) {
        bhd[tid] = (tid < 128) ? ba1[tid] : bc1[tid - 128];
    } else if (bx < 7441) {
        int i = (bx - 7361) * 256 + tid;
        int r = i / 320, c = i - r * 320;
        Wgb[i] = f2bf(c < GLOVE ? Wg[r * GLOVE + c] : 0.f);
    } else if (bx < 7953) {
        int i = (bx - 7441) * 256 + tid;
        int r = i >> 9, c = i & 511;
        W0ab[i] = f2bf(W0[(long)r * 576 + c]);
    } else if (bx < 8209) {
        int i = (bx - 7953) * 256 + tid;
        int r = i >> 7, c = i & 127;
        Wfmb[i] = f2bf(c < 100 ? Wfm[r * 100 + c] : 0.f);
    } else if (bx < 8849) {
        int i = (bx - 8209) * 256 + tid;
        int r = i / 320, c = i - r * 320;
        tgtb[i] = f2bf(c < GLOVE ? target[(long)r * GLOVE + c] : 0.f);
    } else if (bx < 9873) {
        int i = (bx - 8849) * 256 + tid;
        featsb[i] = f2bf(feats[i]);
    } else if (bx < 10897) {
        int i = (bx - 9873) * 256 + tid;
        int r = i >> 9, c = i & 511;
        fusedb[(long)r * FP + c] = f2bf(feats[i]);
    } else if (bx < 10917) {
        int i = (bx - 10897) * 256 + tid;
        int r = i / 10, c6 = i - r * 10;
        float s = ba[c6];
#pragma unroll
        for (int k = 0; k < 6; ++k) s += aprob[r * 6 + k] * Wa[c6 * 6 + k];
        fusedb[(long)r * FP + 576 + c6] = f2bf(fmaxf(s, 0.f));
    } else if (bx < 10961) {
        int i = (bx - 10917) * 256 + tid;
        int r = i / 22, c = 1098 + (i - r * 22);
        fusedb[(long)r * FP + c] = 0;
    } else if (bx < 10993) {
        int i = (bx - 10961) * 256 + tid;          // < 8192 (FULL h0 zero)
        hbA[i] = 0;
    } else if (bx < 10994) {
        if (tid == 0) bar[0] = 0u;
    } else if (bx < 11002) {
        int i = (bx - 10994) * 256 + tid;
        bsum[i] = bih[i] + bhh[i];
    } else if (bx < 11034) {
        int job = (bx - 11002) * 256 + tid;        // < 8192
        int jt = job >> 9, rem = job & 511, kt = rem >> 6, lane = rem & 63;
        int j = jt * 16 + (lane & 15), k0 = kt * 32 + (lane >> 4) * 8;
        const float* src = &W1[(long)j * 256 + k0];
        uint4 p;
        p.x = pk2(src[0], src[1]); p.y = pk2(src[2], src[3]);
        p.z = pk2(src[4], src[5]); p.w = pk2(src[6], src[7]);
        W1f[job] = p;
    } else {
        int job = (bx - 11034) * 256 + tid;        // < 1792
        int mt = job >> 8, rem = job & 255, kt = rem >> 6, lane = rem & 63;
        int m = mt * 16 + (lane & 15), n0 = kt * 32 + (lane >> 4) * 8;
        float h[8];
#pragma unroll
        for (int e = 0; e < 8; ++e)
            h[e] = (m < 100 && n0 + e < 100) ? A[m * 100 + n0 + e] : 0.f;
        uint4 p;
        p.x = pk2(h[0], h[1]); p.y = pk2(h[2], h[3]);
        p.z = pk2(h[4], h[5]); p.w = pk2(h[6], h[7]);
        Af[job] = p;
    }
}

// finish: heads (blocks 0..31) + h/c copy (blocks 32..63)
__global__ void k_finish(const float* __restrict__ hd,
                         const float* __restrict__ Wa2, const float* __restrict__ ba2,
                         const float* __restrict__ Wc2, const float* __restrict__ bc2,
                         const float* __restrict__ hFin, const float* __restrict__ cBuf,
                         float* __restrict__ out)
{
    if (blockIdx.x < 32) {
        int row = blockIdx.x * 16 + (threadIdx.x >> 4);
        int slot = threadIdx.x & 15;
        if (slot < 6) {
            const float4* h4 = (const float4*)(hd + (long)row * 256);
            const float4* w4 = (const float4*)(Wa2 + slot * 128);
            float s = 0.f;
#pragma unroll
            for (int k = 0; k < 32; ++k) {
                float4 h = h4[k], w = w4[k];
                s += h.x * w.x + h.y * w.y + h.z * w.z + h.w * w.w;
            }
            out[row * 6 + slot] = fmaxf(s + ba2[slot], 0.f);
        } else if (slot == 6) {
            const float4* h4 = (const float4*)(hd + (long)row * 256 + 128);
            const float4* w4 = (const float4*)(Wc2);
            float s = 0.f;
#pragma unroll
            for (int k = 0; k < 32; ++k) {
                float4 h = h4[k], w = w4[k];
                s += h.x * w.x + h.y * w.y + h.z * w.z + h.w * w.w;
            }
            out[3072 + row] = fmaxf(s + bc2[0], 0.f);
        }
    } else {
        int i = (blockIdx.x - 32) * 256 + threadIdx.x;   // < 8192
        out[3584 + i] = hFin[i];
        out[11776 + i] = cBuf[i];
    }
}

// ---------------- host ----------------
static inline void mg(hipStream_t st, const unsigned short* A, int lda,
                      const unsigned short* B, int ldb,
                      float* Cf, unsigned short* Cb, int ldc,
                      const float* bias, int M, int N, int K, bool relu, bool bf16out)
{
    dim3 g(N / 64, M / 64), blk(256);
    if (bf16out) {
        if (relu) hipLaunchKernelGGL((mgemm<true, 1>), g, blk, 0, st, A, lda, B, ldb, Cf, Cb, ldc, bias, K);
        else      hipLaunchKernelGGL((mgemm<false, 1>), g, blk, 0, st, A, lda, B, ldb, Cf, Cb, ldc, bias, K);
    } else {
        if (relu) hipLaunchKernelGGL((mgemm<true, 0>), g, blk, 0, st, A, lda, B, ldb, Cf, Cb, ldc, bias, K);
        else      hipLaunchKernelGGL((mgemm<false, 0>), g, blk, 0, st, A, lda, B, ldb, Cf, Cb, ldc, bias, K);
    }
}
static inline void g32(hipStream_t st, const float* A, int lda, const float* B, int ldb,
                       float* C, int ldc, const float* bias, int M, int N, int K, bool relu)
{
    dim3 g((N + 63) / 64, (M + 31) / 32), blk(128);
    if (relu) hipLaunchKernelGGL((gemm32<true>), g, blk, 0, st, A, lda, B, ldb, C, ldc, bias, M, N, K);
    else      hipLaunchKernelGGL((gemm32<false>), g, blk, 0, st, A, lda, B, ldb, C, ldc, bias, M, N, K);
}

extern "C" void kernel_launch(void* const* d_in, const int* in_sizes, int n_in,
                              void* d_out, int out_size, void* d_ws, size_t ws_size,
                              hipStream_t stream)
{
    const float* target = (const float*)d_in[0];
    const float* input_ = (const float*)d_in[1];
    const float* aprob  = (const float*)d_in[2];
    const float* Adj    = (const float*)d_in[3];
    const float* aglove = (const float*)d_in[4];
    const float* Wword  = (const float*)d_in[5];
    const float* bword  = (const float*)d_in[6];
    const float* Wg     = (const float*)d_in[7];
    const float* bg     = (const float*)d_in[8];
    const float* Wa     = (const float*)d_in[9];
    const float* ba     = (const float*)d_in[10];
    const float* W0     = (const float*)d_in[11];
    const float* W1     = (const float*)d_in[12];
    const float* W2     = (const float*)d_in[13];
    const float* Wfm    = (const float*)d_in[14];
    const float* bfm    = (const float*)d_in[15];
    const float* Wf     = (const float*)d_in[16];
    const float* bf     = (const float*)d_in[17];
    const float* Wih    = (const float*)d_in[18];
    const float* Whh    = (const float*)d_in[19];
    const float* bih    = (const float*)d_in[20];
    const float* bhh    = (const float*)d_in[21];
    const float* Wa1    = (const float*)d_in[22];
    const float* ba1    = (const float*)d_in[23];
    const float* Wa2    = (const float*)d_in[24];
    const float* ba2    = (const float*)d_in[25];
    const float* Wc1    = (const float*)d_in[26];
    const float* bc1    = (const float*)d_in[27];
    const float* Wc2    = (const float*)d_in[28];
    const float* bc2    = (const float*)d_in[29];

    float* ws = (float*)d_ws;
    float* out = (float*)d_out;

    size_t off = 0;
    auto alloc = [&](size_t n) { size_t r = off; off += (n + 255) & ~(size_t)255; return r; };
    float* u       = ws + alloc(512 * 256);
    float* word    = ws + alloc(100 * 64);
    float* Aw      = ws + alloc(100 * 64);
    float* rowsum  = ws + alloc(128);
    float* v       = ws + alloc(100 * 256);
    float* bsum    = ws + alloc(2048);
    float* bhd     = ws + alloc(256);
    float* xWih    = ws + alloc((size_t)512 * 2048);
    float* hd      = ws + alloc(512 * 256);
    float* hFin    = ws + alloc(BSZ * Hh);
    float* cBuf    = ws + alloc(BSZ * Hh);
    float* W1frag  = ws + alloc(32768);
    float* Afrag   = ws + alloc(7168);
    float* Whhf    = ws + alloc((size_t)524288);        // 2 MB bf16 frags
    float* X1gf    = ws + alloc((size_t)512 * 3584 * 4); // 29.4 MB bf16 frags
    unsigned* bar  = (unsigned*)(ws + alloc(256));
    // bf16 buffers (alloc in float units, /2)
    unsigned short* x3b     = (unsigned short*)(ws + alloc(512 * 128 / 2));
    unsigned short* fusedb  = (unsigned short*)(ws + alloc((size_t)512 * FP / 2));
    unsigned short* WfPb    = (unsigned short*)(ws + alloc((size_t)512 * FP / 2));
    unsigned short* outfb   = (unsigned short*)(ws + alloc(512 * 512 / 2));
    unsigned short* Wihb    = (unsigned short*)(ws + alloc((size_t)2048 * 512 / 2));
    unsigned short* Whdb    = (unsigned short*)(ws + alloc(256 * 512 / 2));
    unsigned short* Wgb     = (unsigned short*)(ws + alloc(64 * 320 / 2));
    unsigned short* W0ab    = (unsigned short*)(ws + alloc(256 * 512 / 2));
    unsigned short* Wfmb    = (unsigned short*)(ws + alloc(512 * 128 / 2));
    unsigned short* tgtb    = (unsigned short*)(ws + alloc(512 * 320 / 2));
    unsigned short* featsb  = (unsigned short*)(ws + alloc(512 * 512 / 2));
    unsigned short* sfb     = (unsigned short*)(ws + alloc(512 * 512 / 2));
    unsigned short* hbA     = (unsigned short*)(ws + alloc(BSZ * Hh / 2));
    unsigned short* hbB     = (unsigned short*)(ws + alloc(BSZ * Hh / 2));
    (void)ws_size; (void)in_sizes; (void)n_in; (void)out_size;

    const float* feats = input_; // [512,512]

    // --- preprocessing: all layout/convert/zero in one launch ---
    hipLaunchKernelGGL(k_prep, dim3(11041), dim3(256), 0, stream,
                       Whh, (uint4*)Whhf, Wf, WfPb, Wih, Wihb, Wa1, Wc1, Whdb, ba1, bc1, bhd,
                       Wg, Wgb, W0, W0ab, Wfm, Wfmb, target, tgtb, feats, featsb,
                       fusedb, aprob, Wa, ba, hbA, bar, bih, bhh, bsum,
                       W1, (uint4*)W1frag, Adj, (uint4*)Afrag);

    // --- word branch (tiny fp32) ---
    g32(stream, aglove, GLOVE, Wword, GLOVE, word, 64, bword, 100, 64, GLOVE, false);
    hipLaunchKernelGGL(k_aw_rowsum, dim3(26), dim3(256), 0, stream, Adj, word, Aw, rowsum);
    g32(stream, Aw, 64, W0 + 512, 576, v, 256, nullptr, 100, 256, 64, false);

    // --- MFMA GEMMs: u + glove ---
    mg(stream, featsb, 512, W0ab, 512, u, nullptr, 256, nullptr, 512, 256, 512, false, false);
    mg(stream, tgtb, 320, Wgb, 320, nullptr, fusedb + 512, FP, bg, 512, 64, 320, true, true);

    // --- GCN middle: pack X1 frags, then barrier-free MFMA core ---
    hipLaunchKernelGGL(x1pack, dim3(Bt), dim3(256), 0, stream, u, v, rowsum, (uint4*)X1gf);
    hipLaunchKernelGGL(gcn_core, dim3(Bt), dim3(256), 0, stream,
                       (const bf16x8*)X1gf, Adj, (const bf16x8*)W1frag, (const bf16x8*)Afrag, W2, x3b);
    mg(stream, x3b, 128, Wfmb, 128, nullptr, fusedb + 586, FP, bfm, 512, 512, 128, false, true);

    // --- trunk ---
    mg(stream, fusedb, FP, WfPb, FP, nullptr, outfb, 512, bf, 512, 512, FP, true, true);
    mg(stream, outfb, 512, Wihb, 512, xWih, nullptr, 2048, bsum, 512, 2048, 512, false, false);

    // --- LSTM: single persistent launch, 32 steps with grid barrier ---
    hipLaunchKernelGGL(lstm_persist, dim3(32), dim3(256), 0, stream,
                       xWih, (const bf16x8*)Whhf, hbA, hbB, cBuf, hFin, sfb, bar);

    // --- heads ---
    mg(stream, sfb, 512, Whdb, 512, hd, nullptr, 256, bhd, 512, 256, 512, true, false);
    hipLaunchKernelGGL(k_finish, dim3(64), dim3(256), 0, stream,
                       hd, Wa2, ba2, Wc2, bc2, hFin, cBuf, out);
}

// Round 11
// 380.334 us; speedup vs baseline: 1.0042x; 1.0042x over previous
//
#include <hip/hip_runtime.h>
#include <cmath>

// ---------------- problem constants ----------------
constexpr int BSZ = 16, T = 32, NOBJ = 100;
constexpr int GLOVE = 300, GEMB = 64, ADIM = 10, GCN_DIM = 512, Hh = 512, ASPACE = 6, RES = 512;
constexpr int Bt = BSZ * T;          // 512
constexpr int FUSED_IN = RES + GEMB + ADIM + GCN_DIM; // 1098
constexpr int FP = 1120;             // padded fused width

typedef __attribute__((ext_vector_type(8))) short bf16x8;
typedef __attribute__((ext_vector_type(4))) float f32x4;

__device__ __forceinline__ unsigned short f2bf(float f) {
    unsigned u = __float_as_uint(f);
    return (unsigned short)((u + 0x7FFFu + ((u >> 16) & 1u)) >> 16);
}
__device__ __forceinline__ unsigned pk2(float a, float b) {
    return (unsigned)f2bf(a) | ((unsigned)f2bf(b) << 16);
}
__device__ __forceinline__ float sigf(float x) { return 1.f / (1.f + __expf(-x)); }

// ---------------- mgemm: C = A @ B^T (+bias)(relu), bf16 in, fp32 acc ----------------
// 4-deep software pipeline, static stage indices (no scratch). Requires K>=128 here (all
// call sites satisfy), M%64==0, N%64==0, K%32==0, lda/ldb%8==0.
template<bool RELU, int OMODE>  // OMODE: 0=fp32 out, 1=bf16 out
__global__ __launch_bounds__(256)
void mgemm(const unsigned short* __restrict__ A, int lda,
           const unsigned short* __restrict__ B, int ldb,
           float* __restrict__ Cf, unsigned short* __restrict__ Cb, int ldc,
           const float* __restrict__ bias, int K)
{
    const int tid = threadIdx.x;
    const int l = tid & 63, wv = tid >> 6;
    const int m0 = blockIdx.y * 64 + wv * 16;
    const int n0 = blockIdx.x * 64;
    const int lr = l & 15, kg = l >> 4;
    const unsigned short* ap = A + (long)(m0 + lr) * lda + kg * 8;
    const unsigned short* bp = B + (long)(n0 + lr) * ldb + kg * 8;
    const int nk = K >> 5;
    f32x4 acc0 = (f32x4){0.f, 0.f, 0.f, 0.f};
    f32x4 acc1 = acc0, acc2 = acc0, acc3 = acc0;
    bf16x8 a_[4], b0_[4], b1_[4], b2_[4], b3_[4];
#pragma unroll
    for (int s = 0; s < 4; ++s) {
        if (s < nk) {
            int k = s * 32;
            a_[s]  = *(const bf16x8*)(ap + k);
            b0_[s] = *(const bf16x8*)(bp + k);
            b1_[s] = *(const bf16x8*)(bp + 16 * ldb + k);
            b2_[s] = *(const bf16x8*)(bp + 32 * ldb + k);
            b3_[s] = *(const bf16x8*)(bp + 48 * ldb + k);
        }
    }
    for (int i = 0; i < nk; i += 4) {
#pragma unroll
        for (int s = 0; s < 4; ++s) {
            if (i + s < nk) {
                acc0 = __builtin_amdgcn_mfma_f32_16x16x32_bf16(a_[s], b0_[s], acc0, 0, 0, 0);
                acc1 = __builtin_amdgcn_mfma_f32_16x16x32_bf16(a_[s], b1_[s], acc1, 0, 0, 0);
                acc2 = __builtin_amdgcn_mfma_f32_16x16x32_bf16(a_[s], b2_[s], acc2, 0, 0, 0);
                acc3 = __builtin_amdgcn_mfma_f32_16x16x32_bf16(a_[s], b3_[s], acc3, 0, 0, 0);
                if (i + s + 4 < nk) {
                    int k = (i + s + 4) * 32;
                    a_[s]  = *(const bf16x8*)(ap + k);
                    b0_[s] = *(const bf16x8*)(bp + k);
                    b1_[s] = *(const bf16x8*)(bp + 16 * ldb + k);
                    b2_[s] = *(const bf16x8*)(bp + 32 * ldb + k);
                    b3_[s] = *(const bf16x8*)(bp + 48 * ldb + k);
                }
            }
        }
    }
    f32x4 av[4] = {acc0, acc1, acc2, acc3};
#pragma unroll
    for (int nf = 0; nf < 4; ++nf) {
        int n = n0 + nf * 16 + lr;
        float bs = bias ? bias[n] : 0.f;
#pragma unroll
        for (int r = 0; r < 4; ++r) {
            float val = av[nf][r] + bs;
            if (RELU) val = fmaxf(val, 0.f);
            long idx = (long)(m0 + kg * 4 + r) * ldc + n;
            if (OMODE == 0) Cf[idx] = val;
            else            Cb[idx] = f2bf(val);
        }
    }
}

// ---------------- fp32 GEMM for tiny ragged cases (word, v) ----------------
template<bool RELU>
__global__ __launch_bounds__(128)
void gemm32(const float* __restrict__ A, int lda,
            const float* __restrict__ B, int ldb,
            float* __restrict__ C, int ldc,
            const float* __restrict__ bias, int M, int N, int K)
{
    __shared__ float As[32][36];
    __shared__ float Bs[32][68];
    const int tid = threadIdx.x;
    const int m0 = blockIdx.y * 32, n0 = blockIdx.x * 64;
    const int mi = tid >> 4, ni = tid & 15;
    float acc[4][4] = {};
    for (int k0 = 0; k0 < K; k0 += 32) {
        __syncthreads();
#pragma unroll
        for (int l = 0; l < 2; ++l) {
            int e = tid + l * 128;
            int row = e >> 3, kq = (e & 7) << 2;
            float4 va = make_float4(0.f, 0.f, 0.f, 0.f);
            if (m0 + row < M && k0 + kq < K)
                va = *(const float4*)&A[(long)(m0 + row) * lda + k0 + kq];
            As[kq + 0][row] = va.x; As[kq + 1][row] = va.y;
            As[kq + 2][row] = va.z; As[kq + 3][row] = va.w;
        }
#pragma unroll
        for (int l = 0; l < 4; ++l) {
            int e = tid + l * 128;
            int row = e >> 3, kq = (e & 7) << 2;
            float4 vb = make_float4(0.f, 0.f, 0.f, 0.f);
            if (n0 + row < N && k0 + kq < K)
                vb = *(const float4*)&B[(long)(n0 + row) * ldb + k0 + kq];
            Bs[kq + 0][row] = vb.x; Bs[kq + 1][row] = vb.y;
            Bs[kq + 2][row] = vb.z; Bs[kq + 3][row] = vb.w;
        }
        __syncthreads();
#pragma unroll
        for (int k = 0; k < 32; ++k) {
            float4 a4 = *(const float4*)&As[k][4 * mi];
            float4 b4 = *(const float4*)&Bs[k][4 * ni];
            acc[0][0] = fmaf(a4.x, b4.x, acc[0][0]); acc[0][1] = fmaf(a4.x, b4.y, acc[0][1]);
            acc[0][2] = fmaf(a4.x, b4.z, acc[0][2]); acc[0][3] = fmaf(a4.x, b4.w, acc[0][3]);
            acc[1][0] = fmaf(a4.y, b4.x, acc[1][0]); acc[1][1] = fmaf(a4.y, b4.y, acc[1][1]);
            acc[1][2] = fmaf(a4.y, b4.z, acc[1][2]); acc[1][3] = fmaf(a4.y, b4.w, acc[1][3]);
            acc[2][0] = fmaf(a4.z, b4.x, acc[2][0]); acc[2][1] = fmaf(a4.z, b4.y, acc[2][1]);
            acc[2][2] = fmaf(a4.z, b4.z, acc[2][2]); acc[2][3] = fmaf(a4.z, b4.w, acc[2][3]);
            acc[3][0] = fmaf(a4.w, b4.x, acc[3][0]); acc[3][1] = fmaf(a4.w, b4.y, acc[3][1]);
            acc[3][2] = fmaf(a4.w, b4.z, acc[3][2]); acc[3][3] = fmaf(a4.w, b4.w, acc[3][3]);
        }
    }
    const int n = n0 + 4 * ni;
    if (n >= N) return;
    float4 bv = make_float4(0.f, 0.f, 0.f, 0.f);
    if (bias) bv = *(const float4*)&bias[n];
#pragma unroll
    for (int r = 0; r < 4; ++r) {
        int m = m0 + 4 * mi + r;
        if (m >= M) continue;
        float4 v;
        v.x = acc[r][0] + bv.x; v.y = acc[r][1] + bv.y;
        v.z = acc[r][2] + bv.z; v.w = acc[r][3] + bv.w;
        if (RELU) {
            v.x = fmaxf(v.x, 0.f); v.y = fmaxf(v.y, 0.f);
            v.z = fmaxf(v.z, 0.f); v.w = fmaxf(v.w, 0.f);
        }
        *(float4*)&C[(long)m * ldc + n] = v;
    }
}

// ---------------- x1pack: generate X1 in MFMA fragment order (bf16) ----------------
// X1g[b*3584 + mt*512 + kt*64 + l] (uint4) = 8 bf16 of X1[b][mt*16+(l&15)][kt*32+(l>>4)*8 ..]
__global__ __launch_bounds__(256)
void x1pack(const float* __restrict__ u, const float* __restrict__ v,
            const float* __restrict__ rowsum, uint4* __restrict__ X1g)
{
    __shared__ float u_lds[256];
    __shared__ float rs_lds[112];
    const int b = blockIdx.x, tid = threadIdx.x;
    u_lds[tid] = u[(long)b * 256 + tid];
    if (tid < 112) rs_lds[tid] = (tid < 100) ? rowsum[tid] : 0.f;
    __syncthreads();
    uint4* outp = X1g + (size_t)b * 3584;
#pragma unroll
    for (int it = 0; it < 14; ++it) {
        int job = it * 256 + tid;
        int l = job & 63;
        int kt = (job >> 6) & 7;
        int mt = job >> 9;
        int n = mt * 16 + (l & 15);
        int k0 = kt * 32 + ((l >> 4) << 3);
        uint4 p = make_uint4(0, 0, 0, 0);
        if (n < 100) {
            float rsn = rs_lds[n];
            float4 u0 = *(const float4*)&u_lds[k0];
            float4 u1 = *(const float4*)&u_lds[k0 + 4];
            const float4* vp = (const float4*)&v[n * 256 + k0];
            float4 v0 = vp[0], v1 = vp[1];
            float x0 = fmaxf(fmaf(rsn, u0.x, v0.x), 0.f), x1 = fmaxf(fmaf(rsn, u0.y, v0.y), 0.f);
            float x2 = fmaxf(fmaf(rsn, u0.z, v0.z), 0.f), x3 = fmaxf(fmaf(rsn, u0.w, v0.w), 0.f);
            float x4 = fmaxf(fmaf(rsn, u1.x, v1.x), 0.f), x5 = fmaxf(fmaf(rsn, u1.y, v1.y), 0.f);
            float x6 = fmaxf(fmaf(rsn, u1.z, v1.z), 0.f), x7 = fmaxf(fmaf(rsn, u1.w, v1.w), 0.f);
            p = make_uint4(pk2(x0, x1), pk2(x2, x3), pk2(x4, x5), pk2(x6, x7));
        }
        outp[job] = p;
    }
}

// ---------------- gcn_core: Z1=X1@W1^T (frag stream, no barriers) -> X2=A@Z1 -> s -> x3 ----------------
constexpr int ZLD = 152;   // Z1T stride in shorts

__global__ __launch_bounds__(256, 2)
void gcn_core(const bf16x8* __restrict__ X1g,   // [b][7mt][8kt][64l] frags
              const float* __restrict__ Aglob,  // [100,100] fp32
              const bf16x8* __restrict__ W1f,   // [16jt][8kt][64l] frags
              const bf16x8* __restrict__ Af,    // [7mt][4kt][64l] frags
              const float* __restrict__ w2,     // [256]
              unsigned short* __restrict__ x3b) // [512,128] bf16
{
    __shared__ unsigned short Z1Ts[128 * ZLD];
    __shared__ float w2l[256];
    __shared__ float spart[4][112];
    __shared__ float sl[112];

    const int b = blockIdx.x, tid = threadIdx.x;
    const int l = tid & 63, wv = tid >> 6;
    const int lrow = l & 15, kg = l >> 4;

    w2l[tid] = w2[tid];
    if (tid < 128) {
        uint4 z = make_uint4(0, 0, 0, 0);
        *(uint4*)&Z1Ts[tid * ZLD + 112] = z;
        *(uint4*)&Z1Ts[tid * ZLD + 120] = z;
    }
    if (tid < 28) x3b[(long)b * 128 + 100 + tid] = 0;
    __syncthreads();

    const bf16x8* xb = X1g + (size_t)b * 3584 + l;

    float sacc[7][4];
#pragma unroll
    for (int mt = 0; mt < 7; ++mt)
#pragma unroll
        for (int r = 0; r < 4; ++r) sacc[mt][r] = 0.f;

    for (int half = 0; half < 2; ++half) {
        f32x4 acc1[7][2];
#pragma unroll
        for (int mt = 0; mt < 7; ++mt)
#pragma unroll
            for (int jtl = 0; jtl < 2; ++jtl) acc1[mt][jtl] = (f32x4){0.f, 0.f, 0.f, 0.f};

#pragma unroll
        for (int kt = 0; kt < 8; ++kt) {
            bf16x8 af[7];
#pragma unroll
            for (int mt = 0; mt < 7; ++mt)
                af[mt] = xb[mt * 512 + kt * 64];
#pragma unroll
            for (int jtl = 0; jtl < 2; ++jtl) {
                int jt = half * 8 + wv * 2 + jtl;
                bf16x8 bfr = W1f[(jt * 8 + kt) * 64 + l];
#pragma unroll
                for (int mt = 0; mt < 7; ++mt)
                    acc1[mt][jtl] = __builtin_amdgcn_mfma_f32_16x16x32_bf16(af[mt], bfr, acc1[mt][jtl], 0, 0, 0);
            }
        }

        // write Z1T (wave-private rows), bf16
#pragma unroll
        for (int mt = 0; mt < 7; ++mt)
#pragma unroll
            for (int jtl = 0; jtl < 2; ++jtl) {
                int jloc = (wv * 2 + jtl) * 16 + lrow;
                f32x4 a = acc1[mt][jtl];
                uint2 zz;
                zz.x = pk2(a[0], a[1]);
                zz.y = pk2(a[2], a[3]);
                *(uint2*)&Z1Ts[jloc * ZLD + mt * 16 + kg * 4] = zz;
            }

        // phase 2: X2 = A @ Z1 (same-wave read of just-written rows)
        bf16x8 bz[2][4];
#pragma unroll
        for (int jtl = 0; jtl < 2; ++jtl)
#pragma unroll
            for (int k2 = 0; k2 < 4; ++k2)
                bz[jtl][k2] = *(const bf16x8*)&Z1Ts[((wv * 2 + jtl) * 16 + lrow) * ZLD + k2 * 32 + kg * 8];
#pragma unroll
        for (int mt = 0; mt < 7; ++mt) {
            bf16x8 aA[4];
#pragma unroll
            for (int k2 = 0; k2 < 4; ++k2) aA[k2] = Af[(mt * 4 + k2) * 64 + l];
#pragma unroll
            for (int jtl = 0; jtl < 2; ++jtl) {
                f32x4 p = (f32x4){0.f, 0.f, 0.f, 0.f};
#pragma unroll
                for (int k2 = 0; k2 < 4; ++k2)
                    p = __builtin_amdgcn_mfma_f32_16x16x32_bf16(aA[k2], bz[jtl][k2], p, 0, 0, 0);
                float w2j = w2l[half * 128 + (wv * 2 + jtl) * 16 + lrow];
#pragma unroll
                for (int r = 0; r < 4; ++r)
                    sacc[mt][r] = fmaf(fmaxf(p[r], 0.f), w2j, sacc[mt][r]);
            }
        }
    }

    // reduce sacc over j (low 4 lane bits) -> spart
#pragma unroll
    for (int mt = 0; mt < 7; ++mt) {
        float s0 = sacc[mt][0], s1 = sacc[mt][1], s2 = sacc[mt][2], s3 = sacc[mt][3];
#pragma unroll
        for (int off = 1; off < 16; off <<= 1) {
            s0 += __shfl_xor(s0, off);
            s1 += __shfl_xor(s1, off);
            s2 += __shfl_xor(s2, off);
            s3 += __shfl_xor(s3, off);
        }
        if (lrow == 0) {
            int m = mt * 16 + kg * 4;
            spart[wv][m + 0] = s0; spart[wv][m + 1] = s1;
            spart[wv][m + 2] = s2; spart[wv][m + 3] = s3;
        }
    }
    __syncthreads();
    if (tid < 112)
        sl[tid] = spart[0][tid] + spart[1][tid] + spart[2][tid] + spart[3][tid];
    __syncthreads();

    // phase 3: x3[b,n] = relu(sum_m A[n,m]*s[m])
    float sv0 = (l < 100) ? sl[l] : 0.f;
    float sv1 = (l + 64 < 100) ? sl[l + 64] : 0.f;
#pragma unroll 5
    for (int i = 0; i < 25; ++i) {
        int n = i * 4 + wv;
        float a0 = (l < 100) ? Aglob[n * 100 + l] : 0.f;
        float a1 = (l + 64 < 100) ? Aglob[n * 100 + l + 64] : 0.f;
        float p = a0 * sv0 + a1 * sv1;
#pragma unroll
        for (int off = 32; off; off >>= 1) p += __shfl_xor(p, off);
        if (l == 0) x3b[(long)b * 128 + n] = f2bf(fmaxf(p, 0.f));
    }
}

// ---------------- persistent LSTM: one launch, 32 steps, grid spin-barrier ----------------
// 32 blocks x 256 thr. Block bid owns jh slice [bid*16,+16); wave g = gate type.
// Whh fragments preloaded to registers (16 x bf16x8). c kept in one register per thread.
__global__ __launch_bounds__(256)
void lstm_persist(const float* __restrict__ xWih,           // [512][2048], rows b*T+t
                  const bf16x8* __restrict__ Whhf,
                  unsigned short* __restrict__ hbA,         // ping (zeroed)
                  unsigned short* __restrict__ hbB,         // pong
                  float* __restrict__ cBuf,                 // [16][512] final c
                  float* __restrict__ hFin,                 // [16][512] final h
                  unsigned short* __restrict__ sfb,
                  unsigned* __restrict__ bar)               // zeroed counter
{
    __shared__ float gl[4][16][17];
    const int tid = threadIdx.x;
    const int l = tid & 63, g = tid >> 6;
    const int bid = blockIdx.x;
    const int jt = g * 32 + bid;
    const int lr = l & 15, kg = l >> 4;
    const bf16x8* wp = Whhf + (size_t)jt * 16 * 64 + l;
    bf16x8 w[16];
#pragma unroll
    for (int kt = 0; kt < 16; ++kt) w[kt] = wp[kt * 64];
    const int fb = tid >> 4, jl = tid & 15;
    const int jh = bid * 16 + jl;
    float c_reg = 0.f;
    const unsigned short* hprev = hbA;
    unsigned short* hnext = hbB;
    for (int t = 0; t < T; ++t) {
        const unsigned short* hp = hprev + lr * 512 + kg * 8;
        f32x4 acc = (f32x4){0.f, 0.f, 0.f, 0.f};
#pragma unroll
        for (int kt = 0; kt < 16; ++kt) {
            bf16x8 a = *(const bf16x8*)(hp + kt * 32);
            acc = __builtin_amdgcn_mfma_f32_16x16x32_bf16(a, w[kt], acc, 0, 0, 0);
        }
#pragma unroll
        for (int r = 0; r < 4; ++r) gl[g][kg * 4 + r][lr] = acc[r];
        __syncthreads();
        const float* xw = xWih + (size_t)(fb * T + t) * 2048;
        float gi = gl[0][fb][jl] + xw[jh];
        float gf = gl[1][fb][jl] + xw[512 + jh];
        float gg = gl[2][fb][jl] + xw[1024 + jh];
        float go = gl[3][fb][jl] + xw[1536 + jh];
        float cn = sigf(gf) * c_reg + sigf(gi) * tanhf(gg);
        float hn = sigf(go) * tanhf(cn);
        c_reg = cn;
        hnext[fb * 512 + jh] = f2bf(hn);
        sfb[(size_t)(fb * T + t) * 512 + jh] = f2bf(hn);
        if (t == T - 1) { hFin[fb * 512 + jh] = hn; cBuf[fb * 512 + jh] = cn; }
        // grid barrier: release h writes, count, acquire
        __syncthreads();                       // drains this block's stores (vmcnt before s_barrier)
        if (tid == 0) {
            __threadfence();                   // device-scope release
            atomicAdd(bar, 1u);
            unsigned target = 32u * (unsigned)(t + 1);
            while (atomicAdd(bar, 0u) < target) { }   // RMW poll at coherence point
            __threadfence();                   // device-scope acquire
        }
        __syncthreads();
        const unsigned short* tmp = hprev; hprev = hnext; hnext = (unsigned short*)tmp;
    }
}

// ---------------- glue kernels ----------------
__global__ void k_aw_rowsum(const float* __restrict__ A, const float* __restrict__ word,
                            float* __restrict__ Aw, float* __restrict__ rowsum)
{
    int i = blockIdx.x * 256 + threadIdx.x;
    if (i < 6400) {
        int n = i / 64, k = i % 64;
        float s = 0.f;
        for (int m = 0; m < 100; ++m) s += A[n * 100 + m] * word[m * 64 + k];
        Aw[i] = s;
    } else if (i < 6500) {
        int n = i - 6400;
        float s = 0.f;
        for (int m = 0; m < 100; ++m) s += A[n * 100 + m];
        rowsum[n] = s;
    }
}

// preprocessing segments (blocks of 256):
//  [0,512)        Whhf bf16 frag-major
//  [512,2752)     WfPb [512][1120] pad bf16
//  [2752,6848)    Wihb [2048][512] bf16
//  [6848,7360)    Whdb [256][512] = Wa1|Wc1 bf16
//  [7360,7361)    bhd = ba1|bc1
//  [7361,7441)    Wgb [64][320] pad bf16
//  [7441,7953)    W0ab [256][512] bf16
//  [7953,8209)    Wfmb [512][128] pad bf16
//  [8209,8849)    tgtb [512][320] pad bf16
//  [8849,9873)    featsb [512][512] bf16
//  [9873,10897)   fusedb cols 0..512 = feats bf16
//  [10897,10917)  fusedb cols 576..586 = act_e
//  [10917,10961)  fusedb cols 1098..1120 = 0
//  [10961,10993)  hbA zero (8192 bf16)
//  [10993,10994)  bar zero
//  [10994,11002)  bsum
//  [11002,11034)  W1frag
//  [11034,11041)  Afrag
__global__ void k_prep(const float* __restrict__ Whh, uint4* __restrict__ Whhf,
                       const float* __restrict__ Wf, unsigned short* __restrict__ WfPb,
                       const float* __restrict__ Wih, unsigned short* __restrict__ Wihb,
                       const float* __restrict__ Wa1, const float* __restrict__ Wc1,
                       unsigned short* __restrict__ Whdb,
                       const float* __restrict__ ba1, const float* __restrict__ bc1,
                       float* __restrict__ bhd,
                       const float* __restrict__ Wg, unsigned short* __restrict__ Wgb,
                       const float* __restrict__ W0, unsigned short* __restrict__ W0ab,
                       const float* __restrict__ Wfm, unsigned short* __restrict__ Wfmb,
                       const float* __restrict__ target, unsigned short* __restrict__ tgtb,
                       const float* __restrict__ feats, unsigned short* __restrict__ featsb,
                       unsigned short* __restrict__ fusedb,
                       const float* __restrict__ aprob, const float* __restrict__ Wa,
                       const float* __restrict__ ba,
                       unsigned short* __restrict__ hbA, unsigned* __restrict__ bar,
                       const float* __restrict__ bih, const float* __restrict__ bhh,
                       float* __restrict__ bsum,
                       const float* __restrict__ W1, uint4* __restrict__ W1f,
                       const float* __restrict__ A, uint4* __restrict__ Af)
{
    int bx = blockIdx.x, tid = threadIdx.x;
    if (bx < 512) {
        int job = bx * 256 + tid;
        int jtkt = job >> 6, ll = job & 63;
        int j = (jtkt >> 4) * 16 + (ll & 15);
        int k0 = (jtkt & 15) * 32 + (ll >> 4) * 8;
        const float* src = &Whh[(long)j * 512 + k0];
        uint4 p;
        p.x = pk2(src[0], src[1]); p.y = pk2(src[2], src[3]);
        p.z = pk2(src[4], src[5]); p.w = pk2(src[6], src[7]);
        Whhf[job] = p;
    } else if (bx < 2752) {
        int i = (bx - 512) * 256 + tid;
        int r = i / FP, c = i - r * FP;
        WfPb[i] = f2bf(c < FUSED_IN ? Wf[(long)r * FUSED_IN + c] : 0.f);
    } else if (bx < 6848) {
        int i = (bx - 2752) * 256 + tid;
        Wihb[i] = f2bf(Wih[i]);
    } else if (bx < 7360) {
        int i = (bx - 6848) * 256 + tid;
        int r = i >> 9, c = i & 511;
        Whdb[i] = f2bf(r < 128 ? Wa1[r * 512 + c] : Wc1[(r - 128) * 512 + c]);
    } else if (bx < 7361) {
        bhd[tid] = (tid < 128) ? ba1[tid] : bc1[tid - 128];
    } else if (bx < 7441) {
        int i = (bx - 7361) * 256 + tid;
        int r = i / 320, c = i - r * 320;
        Wgb[i] = f2bf(c < GLOVE ? Wg[r * GLOVE + c] : 0.f);
    } else if (bx < 7953) {
        int i = (bx - 7441) * 256 + tid;
        int r = i >> 9, c = i & 511;
        W0ab[i] = f2bf(W0[(long)r * 576 + c]);
    } else if (bx < 8209) {
        int i = (bx - 7953) * 256 + tid;
        int r = i >> 7, c = i & 127;
        Wfmb[i] = f2bf(c < 100 ? Wfm[r * 100 + c] : 0.f);
    } else if (bx < 8849) {
        int i = (bx - 8209) * 256 + tid;
        int r = i / 320, c = i - r * 320;
        tgtb[i] = f2bf(c < GLOVE ? target[(long)r * GLOVE + c] : 0.f);
    } else if (bx < 9873) {
        int i = (bx - 8849) * 256 + tid;
        featsb[i] = f2bf(feats[i]);
    } else if (bx < 10897) {
        int i = (bx - 9873) * 256 + tid;
        int r = i >> 9, c = i & 511;
        fusedb[(long)r * FP + c] = f2bf(feats[i]);
    } else if (bx < 10917) {
        int i = (bx - 10897) * 256 + tid;
        int r = i / 10, c6 = i - r * 10;
        float s = ba[c6];
#pragma unroll
        for (int k = 0; k < 6; ++k) s += aprob[r * 6 + k] * Wa[c6 * 6 + k];
        fusedb[(long)r * FP + 576 + c6] = f2bf(fmaxf(s, 0.f));
    } else if (bx < 10961) {
        int i = (bx - 10917) * 256 + tid;
        int r = i / 22, c = 1098 + (i - r * 22);
        fusedb[(long)r * FP + c] = 0;
    } else if (bx < 10993) {
        int i = (bx - 10961) * 256 + tid;          // < 8192 (FULL h0 zero)
        hbA[i] = 0;
    } else if (bx < 10994) {
        if (tid == 0) bar[0] = 0u;
    } else if (bx < 11002) {
        int i = (bx - 10994) * 256 + tid;
        bsum[i] = bih[i] + bhh[i];
    } else if (bx < 11034) {
        int job = (bx - 11002) * 256 + tid;        // < 8192
        int jt = job >> 9, rem = job & 511, kt = rem >> 6, lane = rem & 63;
        int j = jt * 16 + (lane & 15), k0 = kt * 32 + (lane >> 4) * 8;
        const float* src = &W1[(long)j * 256 + k0];
        uint4 p;
        p.x = pk2(src[0], src[1]); p.y = pk2(src[2], src[3]);
        p.z = pk2(src[4], src[5]); p.w = pk2(src[6], src[7]);
        W1f[job] = p;
    } else {
        int job = (bx - 11034) * 256 + tid;        // < 1792
        int mt = job >> 8, rem = job & 255, kt = rem >> 6, lane = rem & 63;
        int m = mt * 16 + (lane & 15), n0 = kt * 32 + (lane >> 4) * 8;
        float h[8];
#pragma unroll
        for (int e = 0; e < 8; ++e)
            h[e] = (m < 100 && n0 + e < 100) ? A[m * 100 + n0 + e] : 0.f;
        uint4 p;
        p.x = pk2(h[0], h[1]); p.y = pk2(h[2], h[3]);
        p.z = pk2(h[4], h[5]); p.w = pk2(h[6], h[7]);
        Af[job] = p;
    }
}

// finish: heads (blocks 0..31) + h/c copy (blocks 32..63)
__global__ void k_finish(const float* __restrict__ hd,
                         const float* __restrict__ Wa2, const float* __restrict__ ba2,
                         const float* __restrict__ Wc2, const float* __restrict__ bc2,
                         const float* __restrict__ hFin, const float* __restrict__ cBuf,
                         float* __restrict__ out)
{
    if (blockIdx.x < 32) {
        int row = blockIdx.x * 16 + (threadIdx.x >> 4);
        int slot = threadIdx.x & 15;
        if (slot < 6) {
            const float4* h4 = (const float4*)(hd + (long)row * 256);
            const float4* w4 = (const float4*)(Wa2 + slot * 128);
            float s = 0.f;
#pragma unroll
            for (int k = 0; k < 32; ++k) {
                float4 h = h4[k], w = w4[k];
                s += h.x * w.x + h.y * w.y + h.z * w.z + h.w * w.w;
            }
            out[row * 6 + slot] = fmaxf(s + ba2[slot], 0.f);
        } else if (slot == 6) {
            const float4* h4 = (const float4*)(hd + (long)row * 256 + 128);
            const float4* w4 = (const float4*)(Wc2);
            float s = 0.f;
#pragma unroll
            for (int k = 0; k < 32; ++k) {
                float4 h = h4[k], w = w4[k];
                s += h.x * w.x + h.y * w.y + h.z * w.z + h.w * w.w;
            }
            out[3072 + row] = fmaxf(s + bc2[0], 0.f);
        }
    } else {
        int i = (blockIdx.x - 32) * 256 + threadIdx.x;   // < 8192
        out[3584 + i] = hFin[i];
        out[11776 + i] = cBuf[i];
    }
}

// ---------------- host ----------------
static inline void mg(hipStream_t st, const unsigned short* A, int lda,
                      const unsigned short* B, int ldb,
                      float* Cf, unsigned short* Cb, int ldc,
                      const float* bias, int M, int N, int K, bool relu, bool bf16out)
{
    dim3 g(N / 64, M / 64), blk(256);
    if (bf16out) {
        if (relu) hipLaunchKernelGGL((mgemm<true, 1>), g, blk, 0, st, A, lda, B, ldb, Cf, Cb, ldc, bias, K);
        else      hipLaunchKernelGGL((mgemm<false, 1>), g, blk, 0, st, A, lda, B, ldb, Cf, Cb, ldc, bias, K);
    } else {
        if (relu) hipLaunchKernelGGL((mgemm<true, 0>), g, blk, 0, st, A, lda, B, ldb, Cf, Cb, ldc, bias, K);
        else      hipLaunchKernelGGL((mgemm<false, 0>), g, blk, 0, st, A, lda, B, ldb, Cf, Cb, ldc, bias, K);
    }
}
static inline void g32(hipStream_t st, const float* A, int lda, const float* B, int ldb,
                       float* C, int ldc, const float* bias, int M, int N, int K, bool relu)
{
    dim3 g((N + 63) / 64, (M + 31) / 32), blk(128);
    if (relu) hipLaunchKernelGGL((gemm32<true>), g, blk, 0, st, A, lda, B, ldb, C, ldc, bias, M, N, K);
    else      hipLaunchKernelGGL((gemm32<false>), g, blk, 0, st, A, lda, B, ldb, C, ldc, bias, M, N, K);
}

extern "C" void kernel_launch(void* const* d_in, const int* in_sizes, int n_in,
                              void* d_out, int out_size, void* d_ws, size_t ws_size,
                              hipStream_t stream)
{
    const float* target = (const float*)d_in[0];
    const float* input_ = (const float*)d_in[1];
    const float* aprob  = (const float*)d_in[2];
    const float* Adj    = (const float*)d_in[3];
    const float* aglove = (const float*)d_in[4];
    const float* Wword  = (const float*)d_in[5];
    const float* bword  = (const float*)d_in[6];
    const float* Wg     = (const float*)d_in[7];
    const float* bg     = (const float*)d_in[8];
    const float* Wa     = (const float*)d_in[9];
    const float* ba     = (const float*)d_in[10];
    const float* W0     = (const float*)d_in[11];
    const float* W1     = (const float*)d_in[12];
    const float* W2     = (const float*)d_in[13];
    const float* Wfm    = (const float*)d_in[14];
    const float* bfm    = (const float*)d_in[15];
    const float* Wf     = (const float*)d_in[16];
    const float* bf     = (const float*)d_in[17];
    const float* Wih    = (const float*)d_in[18];
    const float* Whh    = (const float*)d_in[19];
    const float* bih    = (const float*)d_in[20];
    const float* bhh    = (const float*)d_in[21];
    const float* Wa1    = (const float*)d_in[22];
    const float* ba1    = (const float*)d_in[23];
    const float* Wa2    = (const float*)d_in[24];
    const float* ba2    = (const float*)d_in[25];
    const float* Wc1    = (const float*)d_in[26];
    const float* bc1    = (const float*)d_in[27];
    const float* Wc2    = (const float*)d_in[28];
    const float* bc2    = (const float*)d_in[29];

    float* ws = (float*)d_ws;
    float* out = (float*)d_out;

    size_t off = 0;
    auto alloc = [&](size_t n) { size_t r = off; off += (n + 255) & ~(size_t)255; return r; };
    float* u       = ws + alloc(512 * 256);
    float* word    = ws + alloc(100 * 64);
    float* Aw      = ws + alloc(100 * 64);
    float* rowsum  = ws + alloc(128);
    float* v       = ws + alloc(100 * 256);
    float* bsum    = ws + alloc(2048);
    float* bhd     = ws + alloc(256);
    float* xWih    = ws + alloc((size_t)512 * 2048);
    float* hd      = ws + alloc(512 * 256);
    float* hFin    = ws + alloc(BSZ * Hh);
    float* cBuf    = ws + alloc(BSZ * Hh);
    float* W1frag  = ws + alloc(32768);
    float* Afrag   = ws + alloc(7168);
    float* Whhf    = ws + alloc((size_t)524288);        // 2 MB bf16 frags
    float* X1gf    = ws + alloc((size_t)512 * 3584 * 4); // 29.4 MB bf16 frags
    unsigned* bar  = (unsigned*)(ws + alloc(256));
    // bf16 buffers (alloc in float units, /2)
    unsigned short* x3b     = (unsigned short*)(ws + alloc(512 * 128 / 2));
    unsigned short* fusedb  = (unsigned short*)(ws + alloc((size_t)512 * FP / 2));
    unsigned short* WfPb    = (unsigned short*)(ws + alloc((size_t)512 * FP / 2));
    unsigned short* outfb   = (unsigned short*)(ws + alloc(512 * 512 / 2));
    unsigned short* Wihb    = (unsigned short*)(ws + alloc((size_t)2048 * 512 / 2));
    unsigned short* Whdb    = (unsigned short*)(ws + alloc(256 * 512 / 2));
    unsigned short* Wgb     = (unsigned short*)(ws + alloc(64 * 320 / 2));
    unsigned short* W0ab    = (unsigned short*)(ws + alloc(256 * 512 / 2));
    unsigned short* Wfmb    = (unsigned short*)(ws + alloc(512 * 128 / 2));
    unsigned short* tgtb    = (unsigned short*)(ws + alloc(512 * 320 / 2));
    unsigned short* featsb  = (unsigned short*)(ws + alloc(512 * 512 / 2));
    unsigned short* sfb     = (unsigned short*)(ws + alloc(512 * 512 / 2));
    unsigned short* hbA     = (unsigned short*)(ws + alloc(BSZ * Hh / 2));
    unsigned short* hbB     = (unsigned short*)(ws + alloc(BSZ * Hh / 2));
    (void)ws_size; (void)in_sizes; (void)n_in; (void)out_size;

    const float* feats = input_; // [512,512]

    // --- preprocessing: all layout/convert/zero in one launch ---
    hipLaunchKernelGGL(k_prep, dim3(11041), dim3(256), 0, stream,
                       Whh, (uint4*)Whhf, Wf, WfPb, Wih, Wihb, Wa1, Wc1, Whdb, ba1, bc1, bhd,
                       Wg, Wgb, W0, W0ab, Wfm, Wfmb, target, tgtb, feats, featsb,
                       fusedb, aprob, Wa, ba, hbA, bar, bih, bhh, bsum,
                       W1, (uint4*)W1frag, Adj, (uint4*)Afrag);

    // --- word branch (tiny fp32) ---
    g32(stream, aglove, GLOVE, Wword, GLOVE, word, 64, bword, 100, 64, GLOVE, false);
    hipLaunchKernelGGL(k_aw_rowsum, dim3(26), dim3(256), 0, stream, Adj, word, Aw, rowsum);
    g32(stream, Aw, 64, W0 + 512, 576, v, 256, nullptr, 100, 256, 64, false);

    // --- MFMA GEMMs: u + glove ---
    mg(stream, featsb, 512, W0ab, 512, u, nullptr, 256, nullptr, 512, 256, 512, false, false);
    mg(stream, tgtb, 320, Wgb, 320, nullptr, fusedb + 512, FP, bg, 512, 64, 320, true, true);

    // --- GCN middle: pack X1 frags, then barrier-free MFMA core ---
    hipLaunchKernelGGL(x1pack, dim3(Bt), dim3(256), 0, stream, u, v, rowsum, (uint4*)X1gf);
    hipLaunchKernelGGL(gcn_core, dim3(Bt), dim3(256), 0, stream,
                       (const bf16x8*)X1gf, Adj, (const bf16x8*)W1frag, (const bf16x8*)Afrag, W2, x3b);
    mg(stream, x3b, 128, Wfmb, 128, nullptr, fusedb + 586, FP, bfm, 512, 512, 128, false, true);

    // --- trunk ---
    mg(stream, fusedb, FP, WfPb, FP, nullptr, outfb, 512, bf, 512, 512, FP, true, true);
    mg(stream, outfb, 512, Wihb, 512, xWih, nullptr, 2048, bsum, 512, 2048, 512, false, false);

    // --- LSTM: single persistent launch, 32 steps with grid barrier ---
    hipLaunchKernelGGL(lstm_persist, dim3(32), dim3(256), 0, stream,
                       xWih, (const bf16x8*)Whhf, hbA, hbB, cBuf, hFin, sfb, bar);

    // --- heads ---
    mg(stream, sfb, 512, Whdb, 512, hd, nullptr, 256, bhd, 512, 256, 512, true, false);
    hipLaunchKernelGGL(k_finish, dim3(64), dim3(256), 0, stream,
                       hd, Wa2, ba2, Wc2, bc2, hFin, cBuf, out);
}

// Round 12
// 375.548 us; speedup vs baseline: 1.0170x; 1.0127x over previous
//
#include <hip/hip_runtime.h>
#include <cmath>

// ---------------- problem constants ----------------
constexpr int BSZ = 16, T = 32, NOBJ = 100;
constexpr int GLOVE = 300, GEMB = 64, ADIM = 10, GCN_DIM = 512, Hh = 512, ASPACE = 6, RES = 512;
constexpr int Bt = BSZ * T;          // 512
constexpr int FUSED_IN = RES + GEMB + ADIM + GCN_DIM; // 1098
constexpr int FP = 1120;             // padded fused width

typedef __attribute__((ext_vector_type(8))) short bf16x8;
typedef __attribute__((ext_vector_type(4))) float f32x4;

__device__ __forceinline__ unsigned short f2bf(float f) {
    unsigned u = __float_as_uint(f);
    return (unsigned short)((u + 0x7FFFu + ((u >> 16) & 1u)) >> 16);
}
__device__ __forceinline__ unsigned pk2(float a, float b) {
    return (unsigned)f2bf(a) | ((unsigned)f2bf(b) << 16);
}
__device__ __forceinline__ float sigf(float x) { return 1.f / (1.f + __expf(-x)); }

// ---------------- mgemm: C = A @ B^T (+bias)(relu), bf16 in, fp32 acc ----------------
// 4-deep software pipeline, static stage indices. M%64==0, N%64==0, K%32==0, lda/ldb%8==0.
template<bool RELU, int OMODE>  // OMODE: 0=fp32 out, 1=bf16 out
__global__ __launch_bounds__(256)
void mgemm(const unsigned short* __restrict__ A, int lda,
           const unsigned short* __restrict__ B, int ldb,
           float* __restrict__ Cf, unsigned short* __restrict__ Cb, int ldc,
           const float* __restrict__ bias, int K)
{
    const int tid = threadIdx.x;
    const int l = tid & 63, wv = tid >> 6;
    const int m0 = blockIdx.y * 64 + wv * 16;
    const int n0 = blockIdx.x * 64;
    const int lr = l & 15, kg = l >> 4;
    const unsigned short* ap = A + (long)(m0 + lr) * lda + kg * 8;
    const unsigned short* bp = B + (long)(n0 + lr) * ldb + kg * 8;
    const int nk = K >> 5;
    f32x4 acc0 = (f32x4){0.f, 0.f, 0.f, 0.f};
    f32x4 acc1 = acc0, acc2 = acc0, acc3 = acc0;
    bf16x8 a_[4], b0_[4], b1_[4], b2_[4], b3_[4];
#pragma unroll
    for (int s = 0; s < 4; ++s) {
        if (s < nk) {
            int k = s * 32;
            a_[s]  = *(const bf16x8*)(ap + k);
            b0_[s] = *(const bf16x8*)(bp + k);
            b1_[s] = *(const bf16x8*)(bp + 16 * ldb + k);
            b2_[s] = *(const bf16x8*)(bp + 32 * ldb + k);
            b3_[s] = *(const bf16x8*)(bp + 48 * ldb + k);
        }
    }
    for (int i = 0; i < nk; i += 4) {
#pragma unroll
        for (int s = 0; s < 4; ++s) {
            if (i + s < nk) {
                acc0 = __builtin_amdgcn_mfma_f32_16x16x32_bf16(a_[s], b0_[s], acc0, 0, 0, 0);
                acc1 = __builtin_amdgcn_mfma_f32_16x16x32_bf16(a_[s], b1_[s], acc1, 0, 0, 0);
                acc2 = __builtin_amdgcn_mfma_f32_16x16x32_bf16(a_[s], b2_[s], acc2, 0, 0, 0);
                acc3 = __builtin_amdgcn_mfma_f32_16x16x32_bf16(a_[s], b3_[s], acc3, 0, 0, 0);
                if (i + s + 4 < nk) {
                    int k = (i + s + 4) * 32;
                    a_[s]  = *(const bf16x8*)(ap + k);
                    b0_[s] = *(const bf16x8*)(bp + k);
                    b1_[s] = *(const bf16x8*)(bp + 16 * ldb + k);
                    b2_[s] = *(const bf16x8*)(bp + 32 * ldb + k);
                    b3_[s] = *(const bf16x8*)(bp + 48 * ldb + k);
                }
            }
        }
    }
    f32x4 av[4] = {acc0, acc1, acc2, acc3};
#pragma unroll
    for (int nf = 0; nf < 4; ++nf) {
        int n = n0 + nf * 16 + lr;
        float bs = bias ? bias[n] : 0.f;
#pragma unroll
        for (int r = 0; r < 4; ++r) {
            float val = av[nf][r] + bs;
            if (RELU) val = fmaxf(val, 0.f);
            long idx = (long)(m0 + kg * 4 + r) * ldc + n;
            if (OMODE == 0) Cf[idx] = val;
            else            Cb[idx] = f2bf(val);
        }
    }
}

// ---------------- fp32 GEMM for tiny ragged cases (word, v) ----------------
template<bool RELU>
__global__ __launch_bounds__(128)
void gemm32(const float* __restrict__ A, int lda,
            const float* __restrict__ B, int ldb,
            float* __restrict__ C, int ldc,
            const float* __restrict__ bias, int M, int N, int K)
{
    __shared__ float As[32][36];
    __shared__ float Bs[32][68];
    const int tid = threadIdx.x;
    const int m0 = blockIdx.y * 32, n0 = blockIdx.x * 64;
    const int mi = tid >> 4, ni = tid & 15;
    float acc[4][4] = {};
    for (int k0 = 0; k0 < K; k0 += 32) {
        __syncthreads();
#pragma unroll
        for (int l = 0; l < 2; ++l) {
            int e = tid + l * 128;
            int row = e >> 3, kq = (e & 7) << 2;
            float4 va = make_float4(0.f, 0.f, 0.f, 0.f);
            if (m0 + row < M && k0 + kq < K)
                va = *(const float4*)&A[(long)(m0 + row) * lda + k0 + kq];
            As[kq + 0][row] = va.x; As[kq + 1][row] = va.y;
            As[kq + 2][row] = va.z; As[kq + 3][row] = va.w;
        }
#pragma unroll
        for (int l = 0; l < 4; ++l) {
            int e = tid + l * 128;
            int row = e >> 3, kq = (e & 7) << 2;
            float4 vb = make_float4(0.f, 0.f, 0.f, 0.f);
            if (n0 + row < N && k0 + kq < K)
                vb = *(const float4*)&B[(long)(n0 + row) * ldb + k0 + kq];
            Bs[kq + 0][row] = vb.x; Bs[kq + 1][row] = vb.y;
            Bs[kq + 2][row] = vb.z; Bs[kq + 3][row] = vb.w;
        }
        __syncthreads();
#pragma unroll
        for (int k = 0; k < 32; ++k) {
            float4 a4 = *(const float4*)&As[k][4 * mi];
            float4 b4 = *(const float4*)&Bs[k][4 * ni];
            acc[0][0] = fmaf(a4.x, b4.x, acc[0][0]); acc[0][1] = fmaf(a4.x, b4.y, acc[0][1]);
            acc[0][2] = fmaf(a4.x, b4.z, acc[0][2]); acc[0][3] = fmaf(a4.x, b4.w, acc[0][3]);
            acc[1][0] = fmaf(a4.y, b4.x, acc[1][0]); acc[1][1] = fmaf(a4.y, b4.y, acc[1][1]);
            acc[1][2] = fmaf(a4.y, b4.z, acc[1][2]); acc[1][3] = fmaf(a4.y, b4.w, acc[1][3]);
            acc[2][0] = fmaf(a4.z, b4.x, acc[2][0]); acc[2][1] = fmaf(a4.z, b4.y, acc[2][1]);
            acc[2][2] = fmaf(a4.z, b4.z, acc[2][2]); acc[2][3] = fmaf(a4.z, b4.w, acc[2][3]);
            acc[3][0] = fmaf(a4.w, b4.x, acc[3][0]); acc[3][1] = fmaf(a4.w, b4.y, acc[3][1]);
            acc[3][2] = fmaf(a4.w, b4.z, acc[3][2]); acc[3][3] = fmaf(a4.w, b4.w, acc[3][3]);
        }
    }
    const int n = n0 + 4 * ni;
    if (n >= N) return;
    float4 bv = make_float4(0.f, 0.f, 0.f, 0.f);
    if (bias) bv = *(const float4*)&bias[n];
#pragma unroll
    for (int r = 0; r < 4; ++r) {
        int m = m0 + 4 * mi + r;
        if (m >= M) continue;
        float4 v;
        v.x = acc[r][0] + bv.x; v.y = acc[r][1] + bv.y;
        v.z = acc[r][2] + bv.z; v.w = acc[r][3] + bv.w;
        if (RELU) {
            v.x = fmaxf(v.x, 0.f); v.y = fmaxf(v.y, 0.f);
            v.z = fmaxf(v.z, 0.f); v.w = fmaxf(v.w, 0.f);
        }
        *(float4*)&C[(long)m * ldc + n] = v;
    }
}

// ---------------- x1pack: generate X1 in MFMA fragment order (bf16) ----------------
__global__ __launch_bounds__(256)
void x1pack(const float* __restrict__ u, const float* __restrict__ v,
            const float* __restrict__ rowsum, uint4* __restrict__ X1g)
{
    __shared__ float u_lds[256];
    __shared__ float rs_lds[112];
    const int b = blockIdx.x, tid = threadIdx.x;
    u_lds[tid] = u[(long)b * 256 + tid];
    if (tid < 112) rs_lds[tid] = (tid < 100) ? rowsum[tid] : 0.f;
    __syncthreads();
    uint4* outp = X1g + (size_t)b * 3584;
#pragma unroll
    for (int it = 0; it < 14; ++it) {
        int job = it * 256 + tid;
        int l = job & 63;
        int kt = (job >> 6) & 7;
        int mt = job >> 9;
        int n = mt * 16 + (l & 15);
        int k0 = kt * 32 + ((l >> 4) << 3);
        uint4 p = make_uint4(0, 0, 0, 0);
        if (n < 100) {
            float rsn = rs_lds[n];
            float4 u0 = *(const float4*)&u_lds[k0];
            float4 u1 = *(const float4*)&u_lds[k0 + 4];
            const float4* vp = (const float4*)&v[n * 256 + k0];
            float4 v0 = vp[0], v1 = vp[1];
            float x0 = fmaxf(fmaf(rsn, u0.x, v0.x), 0.f), x1 = fmaxf(fmaf(rsn, u0.y, v0.y), 0.f);
            float x2 = fmaxf(fmaf(rsn, u0.z, v0.z), 0.f), x3 = fmaxf(fmaf(rsn, u0.w, v0.w), 0.f);
            float x4 = fmaxf(fmaf(rsn, u1.x, v1.x), 0.f), x5 = fmaxf(fmaf(rsn, u1.y, v1.y), 0.f);
            float x6 = fmaxf(fmaf(rsn, u1.z, v1.z), 0.f), x7 = fmaxf(fmaf(rsn, u1.w, v1.w), 0.f);
            p = make_uint4(pk2(x0, x1), pk2(x2, x3), pk2(x4, x5), pk2(x6, x7));
        }
        outp[job] = p;
    }
}

// ---------------- gcn_core: Z1=X1@W1^T -> X2=A@Z1 -> s -> x3 ----------------
constexpr int ZLD = 152;   // Z1T stride in shorts

__global__ __launch_bounds__(256, 2)
void gcn_core(const bf16x8* __restrict__ X1g,   // [b][7mt][8kt][64l] frags
              const float* __restrict__ Aglob,  // [100,100] fp32
              const bf16x8* __restrict__ W1f,   // [16jt][8kt][64l] frags
              const bf16x8* __restrict__ Af,    // [7mt][4kt][64l] frags
              const float* __restrict__ w2,     // [256]
              unsigned short* __restrict__ x3b) // [512,128] bf16
{
    __shared__ unsigned short Z1Ts[128 * ZLD];
    __shared__ float w2l[256];
    __shared__ float spart[4][112];
    __shared__ float sl[112];

    const int b = blockIdx.x, tid = threadIdx.x;
    const int l = tid & 63, wv = tid >> 6;
    const int lrow = l & 15, kg = l >> 4;

    w2l[tid] = w2[tid];
    if (tid < 128) {
        uint4 z = make_uint4(0, 0, 0, 0);
        *(uint4*)&Z1Ts[tid * ZLD + 112] = z;
        *(uint4*)&Z1Ts[tid * ZLD + 120] = z;
    }
    if (tid < 28) x3b[(long)b * 128 + 100 + tid] = 0;
    __syncthreads();

    const bf16x8* xb = X1g + (size_t)b * 3584 + l;

    float sacc[7][4];
#pragma unroll
    for (int mt = 0; mt < 7; ++mt)
#pragma unroll
        for (int r = 0; r < 4; ++r) sacc[mt][r] = 0.f;

    for (int half = 0; half < 2; ++half) {
        f32x4 acc1[7][2];
#pragma unroll
        for (int mt = 0; mt < 7; ++mt)
#pragma unroll
            for (int jtl = 0; jtl < 2; ++jtl) acc1[mt][jtl] = (f32x4){0.f, 0.f, 0.f, 0.f};

#pragma unroll
        for (int kt = 0; kt < 8; ++kt) {
            bf16x8 af[7];
#pragma unroll
            for (int mt = 0; mt < 7; ++mt)
                af[mt] = xb[mt * 512 + kt * 64];
#pragma unroll
            for (int jtl = 0; jtl < 2; ++jtl) {
                int jt = half * 8 + wv * 2 + jtl;
                bf16x8 bfr = W1f[(jt * 8 + kt) * 64 + l];
#pragma unroll
                for (int mt = 0; mt < 7; ++mt)
                    acc1[mt][jtl] = __builtin_amdgcn_mfma_f32_16x16x32_bf16(af[mt], bfr, acc1[mt][jtl], 0, 0, 0);
            }
        }

        // write Z1T (wave-private rows), bf16
#pragma unroll
        for (int mt = 0; mt < 7; ++mt)
#pragma unroll
            for (int jtl = 0; jtl < 2; ++jtl) {
                int jloc = (wv * 2 + jtl) * 16 + lrow;
                f32x4 a = acc1[mt][jtl];
                uint2 zz;
                zz.x = pk2(a[0], a[1]);
                zz.y = pk2(a[2], a[3]);
                *(uint2*)&Z1Ts[jloc * ZLD + mt * 16 + kg * 4] = zz;
            }

        // phase 2: X2 = A @ Z1 (same-wave read of just-written rows)
        bf16x8 bz[2][4];
#pragma unroll
        for (int jtl = 0; jtl < 2; ++jtl)
#pragma unroll
            for (int k2 = 0; k2 < 4; ++k2)
                bz[jtl][k2] = *(const bf16x8*)&Z1Ts[((wv * 2 + jtl) * 16 + lrow) * ZLD + k2 * 32 + kg * 8];
#pragma unroll
        for (int mt = 0; mt < 7; ++mt) {
            bf16x8 aA[4];
#pragma unroll
            for (int k2 = 0; k2 < 4; ++k2) aA[k2] = Af[(mt * 4 + k2) * 64 + l];
#pragma unroll
            for (int jtl = 0; jtl < 2; ++jtl) {
                f32x4 p = (f32x4){0.f, 0.f, 0.f, 0.f};
#pragma unroll
                for (int k2 = 0; k2 < 4; ++k2)
                    p = __builtin_amdgcn_mfma_f32_16x16x32_bf16(aA[k2], bz[jtl][k2], p, 0, 0, 0);
                float w2j = w2l[half * 128 + (wv * 2 + jtl) * 16 + lrow];
#pragma unroll
                for (int r = 0; r < 4; ++r)
                    sacc[mt][r] = fmaf(fmaxf(p[r], 0.f), w2j, sacc[mt][r]);
            }
        }
    }

#pragma unroll
    for (int mt = 0; mt < 7; ++mt) {
        float s0 = sacc[mt][0], s1 = sacc[mt][1], s2 = sacc[mt][2], s3 = sacc[mt][3];
#pragma unroll
        for (int off = 1; off < 16; off <<= 1) {
            s0 += __shfl_xor(s0, off);
            s1 += __shfl_xor(s1, off);
            s2 += __shfl_xor(s2, off);
            s3 += __shfl_xor(s3, off);
        }
        if (lrow == 0) {
            int m = mt * 16 + kg * 4;
            spart[wv][m + 0] = s0; spart[wv][m + 1] = s1;
            spart[wv][m + 2] = s2; spart[wv][m + 3] = s3;
        }
    }
    __syncthreads();
    if (tid < 112)
        sl[tid] = spart[0][tid] + spart[1][tid] + spart[2][tid] + spart[3][tid];
    __syncthreads();

    float sv0 = (l < 100) ? sl[l] : 0.f;
    float sv1 = (l + 64 < 100) ? sl[l + 64] : 0.f;
#pragma unroll 5
    for (int i = 0; i < 25; ++i) {
        int n = i * 4 + wv;
        float a0 = (l < 100) ? Aglob[n * 100 + l] : 0.f;
        float a1 = (l + 64 < 100) ? Aglob[n * 100 + l + 64] : 0.f;
        float p = a0 * sv0 + a1 * sv1;
#pragma unroll
        for (int off = 32; off; off >>= 1) p += __shfl_xor(p, off);
        if (l == 0) x3b[(long)b * 128 + n] = f2bf(fmaxf(p, 0.f));
    }
}

// ---------------- persistent LSTM v2: fence-free, agent-scope coherent exchange ----------------
// 32 blocks x 256 thr. Block bid owns jh slice [bid*16,+16); wave g = gate type.
// All cross-block state (h ping-pong, barrier counter) moves via relaxed AGENT-scope
// atomics (coherence-point ops) -> no __threadfence / L2 flush anywhere.
// Ordering: __syncthreads drains each wave's vmcnt before s_barrier, so all h-stores
// are complete at the coherence point before tid0's arrival fetch_add.
union HU { unsigned long long u[2]; bf16x8 v; };

__global__ __launch_bounds__(256)
void lstm_persist2(const float* __restrict__ xWih,           // [512][2048], rows b*T+t
                   const bf16x8* __restrict__ Whhf,
                   unsigned long long* __restrict__ h0,      // [2048] ull (16x512 bf16), zeroed
                   unsigned long long* __restrict__ h1,
                   float* __restrict__ cBuf, float* __restrict__ hFin,
                   unsigned short* __restrict__ sfb,
                   unsigned* __restrict__ bar)               // zeroed counter
{
    __shared__ float gl[4][16][17];
    __shared__ unsigned short htile[16][16];
    const int tid = threadIdx.x;
    const int l = tid & 63, g = tid >> 6;
    const int bid = blockIdx.x;
    const int jt = g * 32 + bid;
    const int lr = l & 15, kg = l >> 4;
    const bf16x8* wp = Whhf + (size_t)jt * 16 * 64 + l;
    bf16x8 w[16];
#pragma unroll
    for (int kt = 0; kt < 16; ++kt) w[kt] = wp[kt * 64];
    const int fb = tid >> 4, jl = tid & 15;
    const int jh = bid * 16 + jl;
    float c_reg = 0.f;
    unsigned long long* hprev = h0;
    unsigned long long* hnext = h1;
    for (int t = 0; t < T; ++t) {
        // --- A-frags: coherent 8B loads from coherence point, batched then consumed ---
        const unsigned long long* hp = hprev + lr * 128 + kg * 2;
        HU hu[16];
#pragma unroll
        for (int kt = 0; kt < 16; ++kt) {
            hu[kt].u[0] = __hip_atomic_load(hp + kt * 8,     __ATOMIC_RELAXED, __HIP_MEMORY_SCOPE_AGENT);
            hu[kt].u[1] = __hip_atomic_load(hp + kt * 8 + 1, __ATOMIC_RELAXED, __HIP_MEMORY_SCOPE_AGENT);
        }
        f32x4 acc = (f32x4){0.f, 0.f, 0.f, 0.f};
#pragma unroll
        for (int kt = 0; kt < 16; ++kt)
            acc = __builtin_amdgcn_mfma_f32_16x16x32_bf16(hu[kt].v, w[kt], acc, 0, 0, 0);
#pragma unroll
        for (int r = 0; r < 4; ++r) gl[g][kg * 4 + r][lr] = acc[r];
        __syncthreads();
        // --- epilogue: gates -> h,c; stage h tile in LDS ---
        const float* xw = xWih + (size_t)(fb * T + t) * 2048;
        float gi = gl[0][fb][jl] + xw[jh];
        float gf = gl[1][fb][jl] + xw[512 + jh];
        float gg = gl[2][fb][jl] + xw[1024 + jh];
        float go = gl[3][fb][jl] + xw[1536 + jh];
        float cn = sigf(gf) * c_reg + sigf(gi) * tanhf(gg);
        float hn = sigf(go) * tanhf(cn);
        c_reg = cn;
        unsigned short hb = f2bf(hn);
        htile[fb][jl] = hb;
        sfb[(size_t)(fb * T + t) * 512 + jh] = hb;
        if (t == T - 1) { hFin[fb * 512 + jh] = hn; cBuf[fb * 512 + jh] = cn; }
        __syncthreads();
        // --- publish h tile: 64 coherent 8B stores ---
        if (tid < 64) {
            int row = tid >> 2, q = tid & 3;
            unsigned long long val = *(const unsigned long long*)&htile[row][q * 4];
            __hip_atomic_store(&hnext[row * 128 + bid * 4 + q], val,
                               __ATOMIC_RELAXED, __HIP_MEMORY_SCOPE_AGENT);
        }
        __syncthreads();   // drains the storing wave's vmcnt -> h visible at coherence point
        // --- fence-free grid barrier: relaxed RMW arrival + relaxed-load poll ---
        if (tid == 0) {
            __hip_atomic_fetch_add(bar, 1u, __ATOMIC_RELAXED, __HIP_MEMORY_SCOPE_AGENT);
            unsigned tgt = 32u * (unsigned)(t + 1);
            while (__hip_atomic_load(bar, __ATOMIC_RELAXED, __HIP_MEMORY_SCOPE_AGENT) < tgt)
                __builtin_amdgcn_s_sleep(1);
        }
        __syncthreads();
        unsigned long long* tmp = hprev; hprev = hnext; hnext = tmp;
    }
}

// ---------------- glue kernels ----------------
__global__ void k_aw_rowsum(const float* __restrict__ A, const float* __restrict__ word,
                            float* __restrict__ Aw, float* __restrict__ rowsum)
{
    int i = blockIdx.x * 256 + threadIdx.x;
    if (i < 6400) {
        int n = i / 64, k = i % 64;
        float s = 0.f;
        for (int m = 0; m < 100; ++m) s += A[n * 100 + m] * word[m * 64 + k];
        Aw[i] = s;
    } else if (i < 6500) {
        int n = i - 6400;
        float s = 0.f;
        for (int m = 0; m < 100; ++m) s += A[n * 100 + m];
        rowsum[n] = s;
    }
}

// preprocessing segments (blocks of 256): see round-7 table; unchanged layout.
__global__ void k_prep(const float* __restrict__ Whh, uint4* __restrict__ Whhf,
                       const float* __restrict__ Wf, unsigned short* __restrict__ WfPb,
                       const float* __restrict__ Wih, unsigned short* __restrict__ Wihb,
                       const float* __restrict__ Wa1, const float* __restrict__ Wc1,
                       unsigned short* __restrict__ Whdb,
                       const float* __restrict__ ba1, const float* __restrict__ bc1,
                       float* __restrict__ bhd,
                       const float* __restrict__ Wg, unsigned short* __restrict__ Wgb,
                       const float* __restrict__ W0, unsigned short* __restrict__ W0ab,
                       const float* __restrict__ Wfm, unsigned short* __restrict__ Wfmb,
                       const float* __restrict__ target, unsigned short* __restrict__ tgtb,
                       const float* __restrict__ feats, unsigned short* __restrict__ featsb,
                       unsigned short* __restrict__ fusedb,
                       const float* __restrict__ aprob, const float* __restrict__ Wa,
                       const float* __restrict__ ba,
                       unsigned short* __restrict__ hbA, unsigned* __restrict__ bar,
                       const float* __restrict__ bih, const float* __restrict__ bhh,
                       float* __restrict__ bsum,
                       const float* __restrict__ W1, uint4* __restrict__ W1f,
                       const float* __restrict__ A, uint4* __restrict__ Af)
{
    int bx = blockIdx.x, tid = threadIdx.x;
    if (bx < 512) {
        int job = bx * 256 + tid;
        int jtkt = job >> 6, ll = job & 63;
        int j = (jtkt >> 4) * 16 + (ll & 15);
        int k0 = (jtkt & 15) * 32 + (ll >> 4) * 8;
        const float* src = &Whh[(long)j * 512 + k0];
        uint4 p;
        p.x = pk2(src[0], src[1]); p.y = pk2(src[2], src[3]);
        p.z = pk2(src[4], src[5]); p.w = pk2(src[6], src[7]);
        Whhf[job] = p;
    } else if (bx < 2752) {
        int i = (bx - 512) * 256 + tid;
        int r = i / FP, c = i - r * FP;
        WfPb[i] = f2bf(c < FUSED_IN ? Wf[(long)r * FUSED_IN + c] : 0.f);
    } else if (bx < 6848) {
        int i = (bx - 2752) * 256 + tid;
        Wihb[i] = f2bf(Wih[i]);
    } else if (bx < 7360) {
        int i = (bx - 6848) * 256 + tid;
        int r = i >> 9, c = i & 511;
        Whdb[i] = f2bf(r < 128 ? Wa1[r * 512 + c] : Wc1[(r - 128) * 512 + c]);
    } else if (bx < 7361) {
        bhd[tid] = (tid < 128) ? ba1[tid] : bc1[tid - 128];
    } else if (bx < 7441) {
        int i = (bx - 7361) * 256 + tid;
        int r = i / 320, c = i - r * 320;
        Wgb[i] = f2bf(c < GLOVE ? Wg[r * GLOVE + c] : 0.f);
    } else if (bx < 7953) {
        int i = (bx - 7441) * 256 + tid;
        int r = i >> 9, c = i & 511;
        W0ab[i] = f2bf(W0[(long)r * 576 + c]);
    } else if (bx < 8209) {
        int i = (bx - 7953) * 256 + tid;
        int r = i >> 7, c = i & 127;
        Wfmb[i] = f2bf(c < 100 ? Wfm[r * 100 + c] : 0.f);
    } else if (bx < 8849) {
        int i = (bx - 8209) * 256 + tid;
        int r = i / 320, c = i - r * 320;
        tgtb[i] = f2bf(c < GLOVE ? target[(long)r * GLOVE + c] : 0.f);
    } else if (bx < 9873) {
        int i = (bx - 8849) * 256 + tid;
        featsb[i] = f2bf(feats[i]);
    } else if (bx < 10897) {
        int i = (bx - 9873) * 256 + tid;
        int r = i >> 9, c = i & 511;
        fusedb[(long)r * FP + c] = f2bf(feats[i]);
    } else if (bx < 10917) {
        int i = (bx - 10897) * 256 + tid;
        int r = i / 10, c6 = i - r * 10;
        float s = ba[c6];
#pragma unroll
        for (int k = 0; k < 6; ++k) s += aprob[r * 6 + k] * Wa[c6 * 6 + k];
        fusedb[(long)r * FP + 576 + c6] = f2bf(fmaxf(s, 0.f));
    } else if (bx < 10961) {
        int i = (bx - 10917) * 256 + tid;
        int r = i / 22, c = 1098 + (i - r * 22);
        fusedb[(long)r * FP + c] = 0;
    } else if (bx < 10993) {
        int i = (bx - 10961) * 256 + tid;          // < 8192 shorts = full h0
        hbA[i] = 0;
    } else if (bx < 10994) {
        if (tid == 0) bar[0] = 0u;
    } else if (bx < 11002) {
        int i = (bx - 10994) * 256 + tid;
        bsum[i] = bih[i] + bhh[i];
    } else if (bx < 11034) {
        int job = (bx - 11002) * 256 + tid;        // < 8192
        int jt = job >> 9, rem = job & 511, kt = rem >> 6, lane = rem & 63;
        int j = jt * 16 + (lane & 15), k0 = kt * 32 + (lane >> 4) * 8;
        const float* src = &W1[(long)j * 256 + k0];
        uint4 p;
        p.x = pk2(src[0], src[1]); p.y = pk2(src[2], src[3]);
        p.z = pk2(src[4], src[5]); p.w = pk2(src[6], src[7]);
        W1f[job] = p;
    } else {
        int job = (bx - 11034) * 256 + tid;        // < 1792
        int mt = job >> 8, rem = job & 255, kt = rem >> 6, lane = rem & 63;
        int m = mt * 16 + (lane & 15), n0 = kt * 32 + (lane >> 4) * 8;
        float h[8];
#pragma unroll
        for (int e = 0; e < 8; ++e)
            h[e] = (m < 100 && n0 + e < 100) ? A[m * 100 + n0 + e] : 0.f;
        uint4 p;
        p.x = pk2(h[0], h[1]); p.y = pk2(h[2], h[3]);
        p.z = pk2(h[4], h[5]); p.w = pk2(h[6], h[7]);
        Af[job] = p;
    }
}

// finish: heads (blocks 0..31) + h/c copy (blocks 32..63)
__global__ void k_finish(const float* __restrict__ hd,
                         const float* __restrict__ Wa2, const float* __restrict__ ba2,
                         const float* __restrict__ Wc2, const float* __restrict__ bc2,
                         const float* __restrict__ hFin, const float* __restrict__ cBuf,
                         float* __restrict__ out)
{
    if (blockIdx.x < 32) {
        int row = blockIdx.x * 16 + (threadIdx.x >> 4);
        int slot = threadIdx.x & 15;
        if (slot < 6) {
            const float4* h4 = (const float4*)(hd + (long)row * 256);
            const float4* w4 = (const float4*)(Wa2 + slot * 128);
            float s = 0.f;
#pragma unroll
            for (int k = 0; k < 32; ++k) {
                float4 h = h4[k], w = w4[k];
                s += h.x * w.x + h.y * w.y + h.z * w.z + h.w * w.w;
            }
            out[row * 6 + slot] = fmaxf(s + ba2[slot], 0.f);
        } else if (slot == 6) {
            const float4* h4 = (const float4*)(hd + (long)row * 256 + 128);
            const float4* w4 = (const float4*)(Wc2);
            float s = 0.f;
#pragma unroll
            for (int k = 0; k < 32; ++k) {
                float4 h = h4[k], w = w4[k];
                s += h.x * w.x + h.y * w.y + h.z * w.z + h.w * w.w;
            }
            out[3072 + row] = fmaxf(s + bc2[0], 0.f);
        }
    } else {
        int i = (blockIdx.x - 32) * 256 + threadIdx.x;   // < 8192
        out[3584 + i] = hFin[i];
        out[11776 + i] = cBuf[i];
    }
}

// ---------------- host ----------------
static inline void mg(hipStream_t st, const unsigned short* A, int lda,
                      const unsigned short* B, int ldb,
                      float* Cf, unsigned short* Cb, int ldc,
                      const float* bias, int M, int N, int K, bool relu, bool bf16out)
{
    dim3 g(N / 64, M / 64), blk(256);
    if (bf16out) {
        if (relu) hipLaunchKernelGGL((mgemm<true, 1>), g, blk, 0, st, A, lda, B, ldb, Cf, Cb, ldc, bias, K);
        else      hipLaunchKernelGGL((mgemm<false, 1>), g, blk, 0, st, A, lda, B, ldb, Cf, Cb, ldc, bias, K);
    } else {
        if (relu) hipLaunchKernelGGL((mgemm<true, 0>), g, blk, 0, st, A, lda, B, ldb, Cf, Cb, ldc, bias, K);
        else      hipLaunchKernelGGL((mgemm<false, 0>), g, blk, 0, st, A, lda, B, ldb, Cf, Cb, ldc, bias, K);
    }
}
static inline void g32(hipStream_t st, const float* A, int lda, const float* B, int ldb,
                       float* C, int ldc, const float* bias, int M, int N, int K, bool relu)
{
    dim3 g((N + 63) / 64, (M + 31) / 32), blk(128);
    if (relu) hipLaunchKernelGGL((gemm32<true>), g, blk, 0, st, A, lda, B, ldb, C, ldc, bias, M, N, K);
    else      hipLaunchKernelGGL((gemm32<false>), g, blk, 0, st, A, lda, B, ldb, C, ldc, bias, M, N, K);
}

extern "C" void kernel_launch(void* const* d_in, const int* in_sizes, int n_in,
                              void* d_out, int out_size, void* d_ws, size_t ws_size,
                              hipStream_t stream)
{
    const float* target = (const float*)d_in[0];
    const float* input_ = (const float*)d_in[1];
    const float* aprob  = (const float*)d_in[2];
    const float* Adj    = (const float*)d_in[3];
    const float* aglove = (const float*)d_in[4];
    const float* Wword  = (const float*)d_in[5];
    const float* bword  = (const float*)d_in[6];
    const float* Wg     = (const float*)d_in[7];
    const float* bg     = (const float*)d_in[8];
    const float* Wa     = (const float*)d_in[9];
    const float* ba     = (const float*)d_in[10];
    const float* W0     = (const float*)d_in[11];
    const float* W1     = (const float*)d_in[12];
    const float* W2     = (const float*)d_in[13];
    const float* Wfm    = (const float*)d_in[14];
    const float* bfm    = (const float*)d_in[15];
    const float* Wf     = (const float*)d_in[16];
    const float* bf     = (const float*)d_in[17];
    const float* Wih    = (const float*)d_in[18];
    const float* Whh    = (const float*)d_in[19];
    const float* bih    = (const float*)d_in[20];
    const float* bhh    = (const float*)d_in[21];
    const float* Wa1    = (const float*)d_in[22];
    const float* ba1    = (const float*)d_in[23];
    const float* Wa2    = (const float*)d_in[24];
    const float* ba2    = (const float*)d_in[25];
    const float* Wc1    = (const float*)d_in[26];
    const float* bc1    = (const float*)d_in[27];
    const float* Wc2    = (const float*)d_in[28];
    const float* bc2    = (const float*)d_in[29];

    float* ws = (float*)d_ws;
    float* out = (float*)d_out;

    size_t off = 0;
    auto alloc = [&](size_t n) { size_t r = off; off += (n + 255) & ~(size_t)255; return r; };
    float* u       = ws + alloc(512 * 256);
    float* word    = ws + alloc(100 * 64);
    float* Aw      = ws + alloc(100 * 64);
    float* rowsum  = ws + alloc(128);
    float* v       = ws + alloc(100 * 256);
    float* bsum    = ws + alloc(2048);
    float* bhd     = ws + alloc(256);
    float* xWih    = ws + alloc((size_t)512 * 2048);
    float* hd      = ws + alloc(512 * 256);
    float* hFin    = ws + alloc(BSZ * Hh);
    float* cBuf    = ws + alloc(BSZ * Hh);
    float* W1frag  = ws + alloc(32768);
    float* Afrag   = ws + alloc(7168);
    float* Whhf    = ws + alloc((size_t)524288);        // 2 MB bf16 frags
    float* X1gf    = ws + alloc((size_t)512 * 3584 * 4); // 29.4 MB bf16 frags
    unsigned* bar  = (unsigned*)(ws + alloc(256));
    // bf16 buffers (alloc in float units, /2)
    unsigned short* x3b     = (unsigned short*)(ws + alloc(512 * 128 / 2));
    unsigned short* fusedb  = (unsigned short*)(ws + alloc((size_t)512 * FP / 2));
    unsigned short* WfPb    = (unsigned short*)(ws + alloc((size_t)512 * FP / 2));
    unsigned short* outfb   = (unsigned short*)(ws + alloc(512 * 512 / 2));
    unsigned short* Wihb    = (unsigned short*)(ws + alloc((size_t)2048 * 512 / 2));
    unsigned short* Whdb    = (unsigned short*)(ws + alloc(256 * 512 / 2));
    unsigned short* Wgb     = (unsigned short*)(ws + alloc(64 * 320 / 2));
    unsigned short* W0ab    = (unsigned short*)(ws + alloc(256 * 512 / 2));
    unsigned short* Wfmb    = (unsigned short*)(ws + alloc(512 * 128 / 2));
    unsigned short* tgtb    = (unsigned short*)(ws + alloc(512 * 320 / 2));
    unsigned short* featsb  = (unsigned short*)(ws + alloc(512 * 512 / 2));
    unsigned short* sfb     = (unsigned short*)(ws + alloc(512 * 512 / 2));
    unsigned short* hbA     = (unsigned short*)(ws + alloc(BSZ * Hh / 2));
    unsigned short* hbB     = (unsigned short*)(ws + alloc(BSZ * Hh / 2));
    (void)ws_size; (void)in_sizes; (void)n_in; (void)out_size;

    const float* feats = input_; // [512,512]

    // --- preprocessing: all layout/convert/zero in one launch ---
    hipLaunchKernelGGL(k_prep, dim3(11041), dim3(256), 0, stream,
                       Whh, (uint4*)Whhf, Wf, WfPb, Wih, Wihb, Wa1, Wc1, Whdb, ba1, bc1, bhd,
                       Wg, Wgb, W0, W0ab, Wfm, Wfmb, target, tgtb, feats, featsb,
                       fusedb, aprob, Wa, ba, hbA, bar, bih, bhh, bsum,
                       W1, (uint4*)W1frag, Adj, (uint4*)Afrag);

    // --- word branch (tiny fp32) ---
    g32(stream, aglove, GLOVE, Wword, GLOVE, word, 64, bword, 100, 64, GLOVE, false);
    hipLaunchKernelGGL(k_aw_rowsum, dim3(26), dim3(256), 0, stream, Adj, word, Aw, rowsum);
    g32(stream, Aw, 64, W0 + 512, 576, v, 256, nullptr, 100, 256, 64, false);

    // --- MFMA GEMMs: u + glove ---
    mg(stream, featsb, 512, W0ab, 512, u, nullptr, 256, nullptr, 512, 256, 512, false, false);
    mg(stream, tgtb, 320, Wgb, 320, nullptr, fusedb + 512, FP, bg, 512, 64, 320, true, true);

    // --- GCN middle: pack X1 frags, then barrier-free MFMA core ---
    hipLaunchKernelGGL(x1pack, dim3(Bt), dim3(256), 0, stream, u, v, rowsum, (uint4*)X1gf);
    hipLaunchKernelGGL(gcn_core, dim3(Bt), dim3(256), 0, stream,
                       (const bf16x8*)X1gf, Adj, (const bf16x8*)W1frag, (const bf16x8*)Afrag, W2, x3b);
    mg(stream, x3b, 128, Wfmb, 128, nullptr, fusedb + 586, FP, bfm, 512, 512, 128, false, true);

    // --- trunk ---
    mg(stream, fusedb, FP, WfPb, FP, nullptr, outfb, 512, bf, 512, 512, FP, true, true);
    mg(stream, outfb, 512, Wihb, 512, xWih, nullptr, 2048, bsum, 512, 2048, 512, false, false);

    // --- LSTM: single persistent launch, fence-free coherent exchange ---
    hipLaunchKernelGGL(lstm_persist2, dim3(32), dim3(256), 0, stream,
                       xWih, (const bf16x8*)Whhf,
                       (unsigned long long*)hbA, (unsigned long long*)hbB,
                       cBuf, hFin, sfb, bar);

    // --- heads ---
    mg(stream, sfb, 512, Whdb, 512, hd, nullptr, 256, bhd, 512, 256, 512, true, false);
    hipLaunchKernelGGL(k_finish, dim3(64), dim3(256), 0, stream,
                       hd, Wa2, ba2, Wc2, bc2, hFin, cBuf, out);
}